// Round 6
// baseline (1256.590 us; speedup 1.0000x reference)
//
#include <hip/hip_runtime.h>
#include <math.h>

#define D 256
#define E 4
#define H 8
#define LYR 8
#define IMG 128
#define BB 8
#define NC 10
#define T 1024
#define NPER 256
#define DH 32
#define D4 1024

using bf16x8 = __attribute__((ext_vector_type(8))) __bf16;
using bf16x4 = __attribute__((ext_vector_type(4))) __bf16;
using f32x4  = __attribute__((ext_vector_type(4))) float;

#define MFMA16(a, b, c) __builtin_amdgcn_mfma_f32_16x16x32_bf16((a), (b), (c), 0, 0, 0)

// ---------------- single cast kernel for all 6 weight tensors ----------------
__global__ void cast6(const float* __restrict__ s0, const float* __restrict__ s1,
                      const float* __restrict__ s2, const float* __restrict__ s3,
                      const float* __restrict__ s4, const float* __restrict__ s5,
                      __bf16* __restrict__ d0, __bf16* __restrict__ d1,
                      __bf16* __restrict__ d2, __bf16* __restrict__ d3,
                      __bf16* __restrict__ d4, __bf16* __restrict__ d5) {
    const long A4 = (long)LYR * D * D / 4;
    const long W4 = (long)LYR * D4 * D / 4;
    long i = (long)blockIdx.x * 256 + threadIdx.x;
    const float* s; __bf16* d; long off;
    if (i < 4 * A4) {
        int w = (int)(i / A4); off = i - (long)w * A4;
        s = w == 0 ? s0 : w == 1 ? s1 : w == 2 ? s2 : s3;
        d = w == 0 ? d0 : w == 1 ? d1 : w == 2 ? d2 : d3;
    } else {
        long j = i - 4 * A4;
        int w = (int)(j / W4); off = j - (long)w * W4;
        s = w ? s5 : s4; d = w ? d5 : d4;
    }
    float4 v = ((const float4*)s)[off];
    bf16x4 o;
    o[0] = (__bf16)v.x; o[1] = (__bf16)v.y; o[2] = (__bf16)v.z; o[3] = (__bf16)v.w;
    ((bf16x4*)d)[off] = o;
}

// ---------------- fused patch embed + pos emb + router softmax (fp32, exact) -------------
__global__ void patch_router(const float* __restrict__ x, const float* __restrict__ pw,
                             const float* __restrict__ pb, const float* __restrict__ pos,
                             const float* __restrict__ rw, const float* __restrict__ rb,
                             float* __restrict__ tok, float* __restrict__ rawp) {
    int t = blockIdx.x, b = blockIdx.y, d = threadIdx.x;
    __shared__ float sx[48];
    __shared__ float srow[D];
    __shared__ float slog[4];
    int ph = t >> 5, pwc = t & 31;
    if (d < 48) {
        int c = d >> 4, ij = d & 15, i = ij >> 2, j = ij & 3;
        sx[d] = x[(((long)b * 3 + c) * IMG + (ph * 4 + i)) * IMG + (pwc * 4 + j)];
    }
    __syncthreads();
    float acc = pb[d];
    #pragma unroll
    for (int kk = 0; kk < 48; ++kk) acc += sx[kk] * pw[d * 48 + kk];
    float val = acc + pos[(long)t * D + d];
    tok[((long)b * T + t) * D + d] = val;
    srow[d] = val;
    __syncthreads();
    int wv = d >> 6, lane = d & 63;
    float a = 0.f;
    for (int c = lane; c < D; c += 64) a += srow[c] * rw[wv * D + c];
    for (int off = 32; off; off >>= 1) a += __shfl_down(a, off);
    if (lane == 0) slog[wv] = a + rb[wv];
    __syncthreads();
    if (d == 0) {
        float l0 = slog[0], l1 = slog[1], l2 = slog[2], l3 = slog[3];
        float mx = fmaxf(fmaxf(l0, l1), fmaxf(l2, l3));
        float e0 = __expf(l0 - mx), e1 = __expf(l1 - mx), e2 = __expf(l2 - mx), e3 = __expf(l3 - mx);
        float inv = 1.0f / (e0 + e1 + e2 + e3);
        long row = (long)b * T + t;
        rawp[row * 4 + 0] = e0 * inv;
        rawp[row * 4 + 1] = e1 * inv;
        rawp[row * 4 + 2] = e2 * inv;
        rawp[row * 4 + 3] = e3 * inv;
    }
}

// ---------------- greedy routing via MSB-first radix select (partition-exact) ----------------
__global__ __launch_bounds__(1024) void route_topk(const float* __restrict__ rawp,
                                                   int* __restrict__ perm,
                                                   float* __restrict__ rpsel) {
    int b = blockIdx.x, tid = threadIdx.x;
    int lane = tid & 63, wv = tid >> 6;
    __shared__ unsigned hist[256];
    __shared__ unsigned long long ball[16];
    __shared__ int sb_bin, sb_rem;
    bool assigned = false;
    for (int e = 0; e < E; ++e) {
        float v = rawp[((long)b * T + tid) * E + e];
        unsigned key = assigned ? 0u : __float_as_uint(v);
        unsigned prefix = 0;
        int rem = NPER;
        #pragma unroll
        for (int pass = 3; pass >= 0; --pass) {
            int shift = pass * 8;
            if (tid < 256) hist[tid] = 0;
            __syncthreads();
            bool active = (pass == 3) || ((key >> (shift + 8)) == prefix);
            if (active) atomicAdd(&hist[(key >> shift) & 255], 1u);
            __syncthreads();
            if (tid < 64) {
                unsigned c[4], psum = 0;
                #pragma unroll
                for (int u = 0; u < 4; ++u) { c[u] = hist[tid * 4 + u]; psum += c[u]; }
                unsigned suf = psum;
                #pragma unroll
                for (int off = 1; off < 64; off <<= 1) {
                    unsigned o = __shfl_down(suf, off);
                    if (tid + off < 64) suf += o;
                }
                unsigned El = suf - psum;
                if (El < (unsigned)rem && (unsigned)rem <= suf) {
                    unsigned cab = El;
                    #pragma unroll
                    for (int u = 3; u >= 0; --u) {
                        if ((unsigned)rem > cab && (unsigned)rem <= cab + c[u]) {
                            sb_bin = tid * 4 + u;
                            sb_rem = (int)((unsigned)rem - cab);
                        }
                        cab += c[u];
                    }
                }
            }
            __syncthreads();
            prefix = (prefix << 8) | (unsigned)sb_bin;
            rem = sb_rem;
        }
        unsigned t = prefix;
        bool is_tie = (!assigned) && (key == t);
        unsigned long long mbt = __ballot(is_tie);
        if (lane == 0) ball[wv] = mbt;
        __syncthreads();
        int tierank = 0;
        for (int w2 = 0; w2 < wv; ++w2) tierank += __popcll(ball[w2]);
        tierank += __popcll(mbt & ((1ULL << lane) - 1));
        bool sel = (!assigned) && ((key > t) || (is_tie && tierank < rem));
        __syncthreads();
        unsigned long long mbs = __ballot(sel);
        if (lane == 0) ball[wv] = mbs;
        __syncthreads();
        int rank = 0;
        for (int w2 = 0; w2 < wv; ++w2) rank += __popcll(ball[w2]);
        rank += __popcll(mbs & ((1ULL << lane) - 1));
        if (sel) {
            perm[(long)b * T + e * NPER + rank] = tid;
            rpsel[(long)b * T + e * NPER + rank] = v;
            assigned = true;
        }
        __syncthreads();
    }
}

// ---------------- gather tokens into routed order (fp32) ----------------
__global__ void gather_tokens(const float* __restrict__ tok, const int* __restrict__ perm,
                              float* __restrict__ xs) {
    int slot = blockIdx.x, b = blockIdx.y, d = threadIdx.x;
    int src = perm[(long)b * T + slot];
    xs[((long)b * T + slot) * D + d] = tok[((long)b * T + src) * D + d];
}

// ---------------- LN of 32 rows into padded LDS (16 lanes per row, shuffle reduce) --------
__device__ __forceinline__ void ln_rows32(const float* __restrict__ src,
                                          const float* __restrict__ g,
                                          const float* __restrict__ bta,
                                          __bf16 (*slds)[264], int tid) {
    int sub = tid & 15, rowh = tid >> 4;
    int col0 = sub * 16;
    float gv[16], bv[16];
    #pragma unroll
    for (int u = 0; u < 4; ++u) {
        float4 gg = *(const float4*)&g[col0 + 4 * u];
        float4 bb = *(const float4*)&bta[col0 + 4 * u];
        gv[4*u] = gg.x; gv[4*u+1] = gg.y; gv[4*u+2] = gg.z; gv[4*u+3] = gg.w;
        bv[4*u] = bb.x; bv[4*u+1] = bb.y; bv[4*u+2] = bb.z; bv[4*u+3] = bb.w;
    }
    #pragma unroll
    for (int half = 0; half < 2; ++half) {
        int r = rowh + half * 16;
        const float* rp = src + (long)r * D + col0;
        float v[16];
        #pragma unroll
        for (int u = 0; u < 4; ++u) {
            float4 vv = *(const float4*)&rp[4 * u];
            v[4*u] = vv.x; v[4*u+1] = vv.y; v[4*u+2] = vv.z; v[4*u+3] = vv.w;
        }
        float s = 0.f;
        #pragma unroll
        for (int u = 0; u < 16; ++u) s += v[u];
        #pragma unroll
        for (int mk = 1; mk < 16; mk <<= 1) s += __shfl_xor(s, mk);
        float mu = s * (1.0f / D);
        float s2 = 0.f;
        #pragma unroll
        for (int u = 0; u < 16; ++u) { v[u] -= mu; s2 += v[u] * v[u]; }
        #pragma unroll
        for (int mk = 1; mk < 16; mk <<= 1) s2 += __shfl_xor(s2, mk);
        float rstd = rsqrtf(s2 * (1.0f / D) + 1e-5f);
        bf16x8 o0, o1;
        #pragma unroll
        for (int u = 0; u < 8; ++u) o0[u] = (__bf16)(v[u] * rstd * gv[u] + bv[u]);
        #pragma unroll
        for (int u = 0; u < 8; ++u) o1[u] = (__bf16)(v[8+u] * rstd * gv[8+u] + bv[8+u]);
        *(bf16x8*)&slds[r][col0]     = o0;
        *(bf16x8*)&slds[r][col0 + 8] = o1;
    }
}

// ---------------- MFMA GEMM core, compile-time K: full unroll (K<=256) or 4x (K=1024) -----
template<int RG, int K>
__device__ __forceinline__ void gemm_tile(
    const __bf16* __restrict__ A, int lda,
    const __bf16* __restrict__ W, int ldb,
    int lane, f32x4 (&acc)[RG][4])
{
    int lr = lane & 15, lk = (lane >> 4) * 8;
    const __bf16* a0 = A + (long)lr * lda + lk;
    const __bf16* b0 = W + (long)lr * ldb + lk;
    const __bf16* b1 = b0 + 16 * ldb;
    const __bf16* b2 = b0 + 32 * ldb;
    const __bf16* b3 = b0 + 48 * ldb;
    constexpr int CH = (K <= 256) ? K : 128;
    for (int kb = 0; kb < K; kb += CH) {
        #pragma unroll
        for (int ku = 0; ku < CH; ku += 32) {
            int k = kb + ku;
            bf16x8 av[RG];
            #pragma unroll
            for (int i = 0; i < RG; ++i) av[i] = *(const bf16x8*)(a0 + i * 16 * lda + k);
            bf16x8 bv0 = *(const bf16x8*)(b0 + k);
            bf16x8 bv1 = *(const bf16x8*)(b1 + k);
            bf16x8 bv2 = *(const bf16x8*)(b2 + k);
            bf16x8 bv3 = *(const bf16x8*)(b3 + k);
            #pragma unroll
            for (int i = 0; i < RG; ++i) {
                acc[i][0] = MFMA16(av[i], bv0, acc[i][0]);
                acc[i][1] = MFMA16(av[i], bv1, acc[i][1]);
                acc[i][2] = MFMA16(av[i], bv2, acc[i][2]);
                acc[i][3] = MFMA16(av[i], bv3, acc[i][3]);
            }
        }
    }
}

#define GEMM_K_DISPATCH(RG, Aexpr, lda, Wexpr, ldb, accv)                        \
    switch (m) {                                                                 \
      case 256: gemm_tile<RG, 256>(Aexpr, lda, Wexpr, ldb, lane, accv); break;   \
      case 128: gemm_tile<RG, 128>(Aexpr, lda, Wexpr, ldb, lane, accv); break;   \
      case 64:  gemm_tile<RG, 64>(Aexpr, lda, Wexpr, ldb, lane, accv); break;    \
      default:  gemm_tile<RG, 32>(Aexpr, lda, Wexpr, ldb, lane, accv); break;    \
    }

// ---------------- fused LN1 + QKV projection (block: 32 rows x 256 cols of one of q/k/v) ----
__global__ __launch_bounds__(256) void qkv_ln_gemm(
    const float* __restrict__ xs,
    const __bf16* __restrict__ qwb, const __bf16* __restrict__ kwb, const __bf16* __restrict__ vwb,
    const float* __restrict__ qb, const float* __restrict__ kb, const float* __restrict__ vb,
    const float* __restrict__ g, const float* __restrict__ bta,
    __bf16* __restrict__ Qb, __bf16* __restrict__ Kb, __bf16* __restrict__ Vt)
{
    int tid = threadIdx.x, lane = tid & 63, wid = tid >> 6;
    int tile = blockIdx.x, which = blockIdx.y, b = blockIdx.z;
    int row0 = tile * 32;
    int m = D >> (row0 >> 8);
    __shared__ __bf16 slds[32][264];
    ln_rows32(xs + ((long)b * T + row0) * D, g, bta, slds, tid);
    __syncthreads();
    const __bf16* W = which == 0 ? qwb : which == 1 ? kwb : vwb;
    const float* bias = which == 0 ? qb : which == 1 ? kb : vb;
    int ncol0 = wid * 64;
    const f32x4 vz = {0.f, 0.f, 0.f, 0.f};
    f32x4 acc[2][4];
    #pragma unroll
    for (int i = 0; i < 2; ++i) { acc[i][0]=vz; acc[i][1]=vz; acc[i][2]=vz; acc[i][3]=vz; }
    GEMM_K_DISPATCH(2, &slds[0][0], 264, W + (long)ncol0 * D, D, acc)
    int lr = lane & 15, rg = (lane >> 4) * 4;
    #pragma unroll
    for (int i = 0; i < 2; ++i) {
        int row = row0 + i * 16 + rg;
        #pragma unroll
        for (int j = 0; j < 4; ++j) {
            int n = ncol0 + j * 16 + lr;
            float bvs = bias[n];
            if (which == 2) {
                bf16x4 pk;
                #pragma unroll
                for (int r = 0; r < 4; ++r) pk[r] = (__bf16)(acc[i][j][r] + bvs);
                *(bf16x4*)&Vt[((long)b * D + n) * T + row] = pk;
            } else if (which == 0) {
                #pragma unroll
                for (int r = 0; r < 4; ++r)   // fold attention scale 2^-4 into Q
                    Qb[((long)b * T + row + r) * D + n] = (__bf16)((acc[i][j][r] + bvs) * 0.0625f);
            } else {
                #pragma unroll
                for (int r = 0; r < 4; ++r)
                    Kb[((long)b * T + row + r) * D + n] = (__bf16)(acc[i][j][r] + bvs);
            }
        }
    }
}

// ---------------- attention: swapped-QK^T MFMA flash, 16 q/wave, grid 1024, no barriers ----
// XCD pinning: hw assigns XCD ~ bid&7 = batch b; K/V of batch stay in one XCD's L2.
__global__ __launch_bounds__(256) void attn_mfma(
    const __bf16* __restrict__ Qb, const __bf16* __restrict__ Kb,
    const __bf16* __restrict__ Vt, __bf16* __restrict__ aob)
{
    int bid = blockIdx.x;
    int b = bid & 7, h = (bid >> 3) & 7;
    int qt = bid >> 6;
    int lane = threadIdx.x & 63, wave = threadIdx.x >> 6;
    int lr = lane & 15, g = lane >> 4;
    int q0 = qt * 64 + wave * 16;
    __shared__ __bf16 plds[4][16][72];
    const f32x4 vz = {0.f, 0.f, 0.f, 0.f};
    bf16x8 qf = *(const bf16x8*)&Qb[((long)b * T + q0 + lr) * D + h * DH + g * 8];
    f32x4 acc0 = vz, acc1 = vz;
    float ls = 0.f;
    const __bf16* kbase = Kb + (long)b * T * D + h * DH + g * 8;
    const __bf16* vbase = Vt + ((long)b * D + h * DH) * T;
    for (int kc = 0; kc < T; kc += 64) {
        bf16x8 kf[4];
        #pragma unroll
        for (int j = 0; j < 4; ++j)
            kf[j] = *(const bf16x8*)(kbase + (long)(kc + 16 * j + lr) * D);
        bf16x8 vf0[2], vf1[2];
        #pragma unroll
        for (int w = 0; w < 2; ++w) {
            vf0[w] = *(const bf16x8*)(vbase + (long)lr * T        + kc + 32 * w + 8 * g);
            vf1[w] = *(const bf16x8*)(vbase + (long)(16 + lr) * T + kc + 32 * w + 8 * g);
        }
        #pragma unroll
        for (int j = 0; j < 4; ++j) {
            f32x4 s = MFMA16(kf[j], qf, vz);      // S^T: rows=keys(4g+r), cols=queries(lr)
            float p0 = __expf(s[0]), p1 = __expf(s[1]);
            float p2 = __expf(s[2]), p3 = __expf(s[3]);
            ls += (p0 + p1) + (p2 + p3);
            bf16x4 pk;
            pk[0] = (__bf16)p0; pk[1] = (__bf16)p1;
            pk[2] = (__bf16)p2; pk[3] = (__bf16)p3;
            *(bf16x4*)&plds[wave][lr][16 * j + 4 * g] = pk;
        }
        #pragma unroll
        for (int w = 0; w < 2; ++w) {
            bf16x8 pa = *(const bf16x8*)&plds[wave][lr][32 * w + 8 * g];
            acc0 = MFMA16(pa, vf0[w], acc0);
            acc1 = MFMA16(pa, vf1[w], acc1);
        }
    }
    ls += __shfl_xor(ls, 16);
    ls += __shfl_xor(ls, 32);
    float inv = 1.0f / ls;
    #pragma unroll
    for (int r = 0; r < 4; ++r) {
        float invr = __shfl(inv, 4 * g + r);   // sum for query 4g+r lives at lane lr==4g+r
        long obase = ((long)b * T + q0 + 4 * g + r) * D + h * DH;
        aob[obase + lr]      = (__bf16)(acc0[r] * invr);
        aob[obase + 16 + lr] = (__bf16)(acc1[r] * invr);
    }
}

#define GEMM_PROLOGUE \
    int lane = threadIdx.x & 63, wid = threadIdx.x >> 6; \
    int wm = wid >> 1, wn = wid & 1; \
    int b = blockIdx.z >> 2, e = blockIdx.z & 3; \
    int m = D >> e; \
    const f32x4 vz = {0.f, 0.f, 0.f, 0.f}; \
    f32x4 acc[2][4]; \
    _Pragma("unroll") \
    for (int i = 0; i < 2; ++i) { acc[i][0]=vz; acc[i][1]=vz; acc[i][2]=vz; acc[i][3]=vz; }

// ---------------- O projection GEMM + residual into fp32 xs ----------------
__global__ __launch_bounds__(256) void oproj_gemm(
    const __bf16* __restrict__ aob, const __bf16* __restrict__ owb,
    const float* __restrict__ ob, float* __restrict__ xs)
{
    GEMM_PROLOGUE
    if ((int)blockIdx.y * 128 >= m) return;
    int ncol0 = blockIdx.y * 128 + wn * 64;
    int row0 = e * NPER + blockIdx.x * 64 + wm * 32;
    GEMM_K_DISPATCH(2, aob + ((long)b * T + row0) * D, D, owb + (long)ncol0 * D, D, acc)
    int lr = lane & 15, rg = (lane >> 4) * 4;
    #pragma unroll
    for (int i = 0; i < 2; ++i) {
        int row = row0 + i * 16 + rg;
        #pragma unroll
        for (int j = 0; j < 4; ++j) {
            int n = ncol0 + j * 16 + lr;
            if (n < m) {
                float bv = ob[n];
                #pragma unroll
                for (int r = 0; r < 4; ++r)
                    xs[((long)b * T + row + r) * D + n] += acc[i][j][r] + bv;
            }
        }
    }
}

// ---------------- fused LN2 + MLP layer 1 GEMM + exact gelu -> bf16 inner ----------------
__global__ __launch_bounds__(256) void mlp1_ln_gemm(
    const float* __restrict__ xs, const __bf16* __restrict__ w1b,
    const float* __restrict__ b1, const float* __restrict__ g, const float* __restrict__ bta,
    __bf16* __restrict__ innerb)
{
    int tid = threadIdx.x, lane = tid & 63, wid = tid >> 6;
    int tile = blockIdx.x, fq = blockIdx.y, b = blockIdx.z;
    int row0 = tile * 32;
    int m = D >> (row0 >> 8);
    __shared__ __bf16 slds[32][264];
    ln_rows32(xs + ((long)b * T + row0) * D, g, bta, slds, tid);
    __syncthreads();
    int ncol0 = fq * 256 + wid * 64;
    const f32x4 vz = {0.f, 0.f, 0.f, 0.f};
    f32x4 acc[2][4];
    #pragma unroll
    for (int i = 0; i < 2; ++i) { acc[i][0]=vz; acc[i][1]=vz; acc[i][2]=vz; acc[i][3]=vz; }
    GEMM_K_DISPATCH(2, &slds[0][0], 264, w1b + (long)ncol0 * D, D, acc)
    int lr = lane & 15, rg = (lane >> 4) * 4;
    #pragma unroll
    for (int i = 0; i < 2; ++i) {
        int row = row0 + i * 16 + rg;
        #pragma unroll
        for (int j = 0; j < 4; ++j) {
            int f = ncol0 + j * 16 + lr;
            float bv = b1[f];
            #pragma unroll
            for (int r = 0; r < 4; ++r) {
                float xv = acc[i][j][r] + bv;
                float gl = 0.5f * xv * (1.0f + erff(xv * 0.70710678118654752f));
                innerb[((long)b * T + row + r) * D4 + f] = (__bf16)gl;
            }
        }
    }
}

// ---------------- MLP layer 2 GEMM + sf-scaled residual into fp32 xs ----------------
__global__ __launch_bounds__(256) void mlp2_gemm(
    const __bf16* __restrict__ innerb, const __bf16* __restrict__ w2b,
    const float* __restrict__ b2, const float* __restrict__ rpsel,
    const float* __restrict__ alpha, float* __restrict__ xs)
{
    GEMM_PROLOGUE
    if ((int)blockIdx.y * 128 >= m) return;
    int ncol0 = blockIdx.y * 128 + wn * 64;
    int row0 = e * NPER + blockIdx.x * 64 + wm * 32;
    gemm_tile<2, 1024>(innerb + ((long)b * T + row0) * D4, D4,
                       w2b + (long)ncol0 * D4, D4, lane, acc);
    int lr = lane & 15, rg = (lane >> 4) * 4;
    float a0 = alpha[0];
    #pragma unroll
    for (int i = 0; i < 2; ++i) {
        int row = row0 + i * 16 + rg;
        float sf[4];
        #pragma unroll
        for (int r = 0; r < 4; ++r) sf[r] = a0 * rpsel[(long)b * T + row + r] + 1.0f;
        #pragma unroll
        for (int j = 0; j < 4; ++j) {
            int n = ncol0 + j * 16 + lr;
            if (n < m) {
                float bv = b2[n];
                #pragma unroll
                for (int r = 0; r < 4; ++r)
                    xs[((long)b * T + row + r) * D + n] += sf[r] * (acc[i][j][r] + bv);
            }
        }
    }
}

// ---------------- mean pool (2-stage, deterministic) + head ----------------
__global__ void head_partial(const float* __restrict__ xs, float* __restrict__ part) {
    int c = blockIdx.x, b = blockIdx.y, d = threadIdx.x;
    const float* p = xs + ((long)b * T + c * 128) * D + d;
    float s = 0.f;
    #pragma unroll 8
    for (int i = 0; i < 128; ++i) s += p[(long)i * D];
    part[((long)b * 8 + c) * D + d] = s;
}

__global__ void head_final(const float* __restrict__ part, const float* __restrict__ hw,
                           const float* __restrict__ hb, float* __restrict__ out) {
    int b = blockIdx.x, d = threadIdx.x;
    __shared__ float smean[D];
    float s = 0.f;
    #pragma unroll
    for (int c = 0; c < 8; ++c) s += part[((long)b * 8 + c) * D + d];
    smean[d] = s * (1.0f / T);
    __syncthreads();
    if (d < NC) {
        float acc = hb[d];
        for (int c = 0; c < D; ++c) acc += smean[c] * hw[d * D + c];
        out[b * NC + d] = acc;
    }
}

extern "C" void kernel_launch(void* const* d_in, const int* in_sizes, int n_in,
                              void* d_out, int out_size, void* d_ws, size_t ws_size,
                              hipStream_t stream) {
    const float* x      = (const float*)d_in[0];
    const float* patchw = (const float*)d_in[1];
    const float* patchb = (const float*)d_in[2];
    const float* pos    = (const float*)d_in[3];
    const float* rw     = (const float*)d_in[4];
    const float* rb     = (const float*)d_in[5];
    const float* ln1g   = (const float*)d_in[6];
    const float* ln1b   = (const float*)d_in[7];
    const float* qw     = (const float*)d_in[8];
    const float* qbi    = (const float*)d_in[9];
    const float* kw     = (const float*)d_in[10];
    const float* kbi    = (const float*)d_in[11];
    const float* vw     = (const float*)d_in[12];
    const float* vbi    = (const float*)d_in[13];
    const float* ow     = (const float*)d_in[14];
    const float* obi    = (const float*)d_in[15];
    const float* ln2g   = (const float*)d_in[16];
    const float* ln2b   = (const float*)d_in[17];
    const float* l1w    = (const float*)d_in[18];
    const float* l1b    = (const float*)d_in[19];
    const float* l2w    = (const float*)d_in[20];
    const float* l2b    = (const float*)d_in[21];
    const float* hw     = (const float*)d_in[22];
    const float* hb     = (const float*)d_in[23];
    const float* alpha  = (const float*)d_in[24];

    char* p = (char*)d_ws;
    auto alloc = [&](size_t bytes) { void* r = (void*)p; p += (bytes + 255) & ~(size_t)255; return r; };
    const long NTD = (long)BB * T * D;

    float*  tok    = (float*)alloc(NTD * 4);
    float*  xs     = (float*)alloc(NTD * 4);
    float*  rawp   = (float*)alloc((long)BB * T * E * 4);
    float*  rpsel  = (float*)alloc((long)BB * T * 4);
    int*    perm   = (int*)alloc((long)BB * T * 4);
    float*  part   = (float*)alloc((long)BB * 8 * D * 4);
    __bf16* Qb     = (__bf16*)alloc(NTD * 2);
    __bf16* Kb     = (__bf16*)alloc(NTD * 2);
    __bf16* Vt     = (__bf16*)alloc(NTD * 2);
    __bf16* aob    = (__bf16*)alloc(NTD * 2);
    __bf16* innerb = (__bf16*)alloc((long)BB * T * D4 * 2);
    __bf16* qwb    = (__bf16*)alloc((long)LYR * D * D * 2);
    __bf16* kwb    = (__bf16*)alloc((long)LYR * D * D * 2);
    __bf16* vwb    = (__bf16*)alloc((long)LYR * D * D * 2);
    __bf16* owb    = (__bf16*)alloc((long)LYR * D * D * 2);
    __bf16* w1b    = (__bf16*)alloc((long)LYR * D4 * D * 2);
    __bf16* w2b    = (__bf16*)alloc((long)LYR * D * D4 * 2);

    cast6<<<6144, 256, 0, stream>>>(qw, kw, vw, ow, l1w, l2w, qwb, kwb, vwb, owb, w1b, w2b);

    patch_router<<<dim3(T, BB), 256, 0, stream>>>(x, patchw, patchb, pos, rw, rb, tok, rawp);
    route_topk<<<BB, 1024, 0, stream>>>(rawp, perm, rpsel);
    gather_tokens<<<dim3(T, BB), 256, 0, stream>>>(tok, perm, xs);

    for (int l = 0; l < LYR; ++l) {
        qkv_ln_gemm<<<dim3(32, 3, BB), 256, 0, stream>>>(
            xs, qwb + (long)l * D * D, kwb + (long)l * D * D, vwb + (long)l * D * D,
            qbi + l * D, kbi + l * D, vbi + l * D,
            ln1g + l * D, ln1b + l * D, Qb, Kb, Vt);
        attn_mfma<<<dim3(1024), 256, 0, stream>>>(Qb, Kb, Vt, aob);
        oproj_gemm<<<dim3(4, 2, BB * E), 256, 0, stream>>>(
            aob, owb + (long)l * D * D, obi + l * D, xs);
        mlp1_ln_gemm<<<dim3(32, 4, BB), 256, 0, stream>>>(
            xs, w1b + (long)l * D4 * D, l1b + (long)l * D4,
            ln2g + l * D, ln2b + l * D, innerb);
        mlp2_gemm<<<dim3(4, 2, BB * E), 256, 0, stream>>>(
            innerb, w2b + (long)l * D * D4, l2b + l * D, rpsel, alpha, xs);
    }

    head_partial<<<dim3(8, BB), 256, 0, stream>>>(xs, part);
    head_final<<<BB, D, 0, stream>>>(part, hw, hb, (float*)d_out);
}

// Round 7
// 1219.487 us; speedup vs baseline: 1.0304x; 1.0304x over previous
//
#include <hip/hip_runtime.h>
#include <math.h>

#define D 256
#define E 4
#define H 8
#define LYR 8
#define IMG 128
#define BB 8
#define NC 10
#define T 1024
#define NPER 256
#define DH 32
#define D4 1024

using bf16x8 = __attribute__((ext_vector_type(8))) __bf16;
using bf16x4 = __attribute__((ext_vector_type(4))) __bf16;
using f32x4  = __attribute__((ext_vector_type(4))) float;

#define MFMA16(a, b, c) __builtin_amdgcn_mfma_f32_16x16x32_bf16((a), (b), (c), 0, 0, 0)

// ---------------- single cast kernel for all 6 weight tensors ----------------
__global__ void cast6(const float* __restrict__ s0, const float* __restrict__ s1,
                      const float* __restrict__ s2, const float* __restrict__ s3,
                      const float* __restrict__ s4, const float* __restrict__ s5,
                      __bf16* __restrict__ d0, __bf16* __restrict__ d1,
                      __bf16* __restrict__ d2, __bf16* __restrict__ d3,
                      __bf16* __restrict__ d4, __bf16* __restrict__ d5) {
    const long A4 = (long)LYR * D * D / 4;
    const long W4 = (long)LYR * D4 * D / 4;
    long i = (long)blockIdx.x * 256 + threadIdx.x;
    const float* s; __bf16* d; long off;
    if (i < 4 * A4) {
        int w = (int)(i / A4); off = i - (long)w * A4;
        s = w == 0 ? s0 : w == 1 ? s1 : w == 2 ? s2 : s3;
        d = w == 0 ? d0 : w == 1 ? d1 : w == 2 ? d2 : d3;
    } else {
        long j = i - 4 * A4;
        int w = (int)(j / W4); off = j - (long)w * W4;
        s = w ? s5 : s4; d = w ? d5 : d4;
    }
    float4 v = ((const float4*)s)[off];
    bf16x4 o;
    o[0] = (__bf16)v.x; o[1] = (__bf16)v.y; o[2] = (__bf16)v.z; o[3] = (__bf16)v.w;
    ((bf16x4*)d)[off] = o;
}

// ---------------- fused patch embed + pos emb + router softmax (fp32, exact) -------------
__global__ void patch_router(const float* __restrict__ x, const float* __restrict__ pw,
                             const float* __restrict__ pb, const float* __restrict__ pos,
                             const float* __restrict__ rw, const float* __restrict__ rb,
                             float* __restrict__ tok, float* __restrict__ rawp) {
    int t = blockIdx.x, b = blockIdx.y, d = threadIdx.x;
    __shared__ float sx[48];
    __shared__ float srow[D];
    __shared__ float slog[4];
    int ph = t >> 5, pwc = t & 31;
    if (d < 48) {
        int c = d >> 4, ij = d & 15, i = ij >> 2, j = ij & 3;
        sx[d] = x[(((long)b * 3 + c) * IMG + (ph * 4 + i)) * IMG + (pwc * 4 + j)];
    }
    __syncthreads();
    float acc = pb[d];
    #pragma unroll
    for (int kk = 0; kk < 48; ++kk) acc += sx[kk] * pw[d * 48 + kk];
    float val = acc + pos[(long)t * D + d];
    tok[((long)b * T + t) * D + d] = val;
    srow[d] = val;
    __syncthreads();
    int wv = d >> 6, lane = d & 63;
    float a = 0.f;
    for (int c = lane; c < D; c += 64) a += srow[c] * rw[wv * D + c];
    for (int off = 32; off; off >>= 1) a += __shfl_down(a, off);
    if (lane == 0) slog[wv] = a + rb[wv];
    __syncthreads();
    if (d == 0) {
        float l0 = slog[0], l1 = slog[1], l2 = slog[2], l3 = slog[3];
        float mx = fmaxf(fmaxf(l0, l1), fmaxf(l2, l3));
        float e0 = __expf(l0 - mx), e1 = __expf(l1 - mx), e2 = __expf(l2 - mx), e3 = __expf(l3 - mx);
        float inv = 1.0f / (e0 + e1 + e2 + e3);
        long row = (long)b * T + t;
        rawp[row * 4 + 0] = e0 * inv;
        rawp[row * 4 + 1] = e1 * inv;
        rawp[row * 4 + 2] = e2 * inv;
        rawp[row * 4 + 3] = e3 * inv;
    }
}

// ---------------- greedy routing via MSB-first radix select (partition-exact) ----------------
__global__ __launch_bounds__(1024) void route_topk(const float* __restrict__ rawp,
                                                   int* __restrict__ perm,
                                                   float* __restrict__ rpsel) {
    int b = blockIdx.x, tid = threadIdx.x;
    int lane = tid & 63, wv = tid >> 6;
    __shared__ unsigned hist[256];
    __shared__ unsigned long long ball[16];
    __shared__ int sb_bin, sb_rem;
    bool assigned = false;
    for (int e = 0; e < E; ++e) {
        float v = rawp[((long)b * T + tid) * E + e];
        unsigned key = assigned ? 0u : __float_as_uint(v);
        unsigned prefix = 0;
        int rem = NPER;
        #pragma unroll
        for (int pass = 3; pass >= 0; --pass) {
            int shift = pass * 8;
            if (tid < 256) hist[tid] = 0;
            __syncthreads();
            bool active = (pass == 3) || ((key >> (shift + 8)) == prefix);
            if (active) atomicAdd(&hist[(key >> shift) & 255], 1u);
            __syncthreads();
            if (tid < 64) {
                unsigned c[4], psum = 0;
                #pragma unroll
                for (int u = 0; u < 4; ++u) { c[u] = hist[tid * 4 + u]; psum += c[u]; }
                unsigned suf = psum;
                #pragma unroll
                for (int off = 1; off < 64; off <<= 1) {
                    unsigned o = __shfl_down(suf, off);
                    if (tid + off < 64) suf += o;
                }
                unsigned El = suf - psum;
                if (El < (unsigned)rem && (unsigned)rem <= suf) {
                    unsigned cab = El;
                    #pragma unroll
                    for (int u = 3; u >= 0; --u) {
                        if ((unsigned)rem > cab && (unsigned)rem <= cab + c[u]) {
                            sb_bin = tid * 4 + u;
                            sb_rem = (int)((unsigned)rem - cab);
                        }
                        cab += c[u];
                    }
                }
            }
            __syncthreads();
            prefix = (prefix << 8) | (unsigned)sb_bin;
            rem = sb_rem;
        }
        unsigned t = prefix;
        bool is_tie = (!assigned) && (key == t);
        unsigned long long mbt = __ballot(is_tie);
        if (lane == 0) ball[wv] = mbt;
        __syncthreads();
        int tierank = 0;
        for (int w2 = 0; w2 < wv; ++w2) tierank += __popcll(ball[w2]);
        tierank += __popcll(mbt & ((1ULL << lane) - 1));
        bool sel = (!assigned) && ((key > t) || (is_tie && tierank < rem));
        __syncthreads();
        unsigned long long mbs = __ballot(sel);
        if (lane == 0) ball[wv] = mbs;
        __syncthreads();
        int rank = 0;
        for (int w2 = 0; w2 < wv; ++w2) rank += __popcll(ball[w2]);
        rank += __popcll(mbs & ((1ULL << lane) - 1));
        if (sel) {
            perm[(long)b * T + e * NPER + rank] = tid;
            rpsel[(long)b * T + e * NPER + rank] = v;
            assigned = true;
        }
        __syncthreads();
    }
}

// ---------------- gather tokens into routed order (fp32) ----------------
__global__ void gather_tokens(const float* __restrict__ tok, const int* __restrict__ perm,
                              float* __restrict__ xs) {
    int slot = blockIdx.x, b = blockIdx.y, d = threadIdx.x;
    int src = perm[(long)b * T + slot];
    xs[((long)b * T + slot) * D + d] = tok[((long)b * T + src) * D + d];
}

// ---------------- LN of 32 rows into padded LDS (16 lanes per row, shuffle reduce) --------
__device__ __forceinline__ void ln_rows32(const float* __restrict__ src,
                                          const float* __restrict__ g,
                                          const float* __restrict__ bta,
                                          __bf16 (*slds)[264], int tid) {
    int sub = tid & 15, rowh = tid >> 4;
    int col0 = sub * 16;
    float gv[16], bv[16];
    #pragma unroll
    for (int u = 0; u < 4; ++u) {
        float4 gg = *(const float4*)&g[col0 + 4 * u];
        float4 bb = *(const float4*)&bta[col0 + 4 * u];
        gv[4*u] = gg.x; gv[4*u+1] = gg.y; gv[4*u+2] = gg.z; gv[4*u+3] = gg.w;
        bv[4*u] = bb.x; bv[4*u+1] = bb.y; bv[4*u+2] = bb.z; bv[4*u+3] = bb.w;
    }
    #pragma unroll
    for (int half = 0; half < 2; ++half) {
        int r = rowh + half * 16;
        const float* rp = src + (long)r * D + col0;
        float v[16];
        #pragma unroll
        for (int u = 0; u < 4; ++u) {
            float4 vv = *(const float4*)&rp[4 * u];
            v[4*u] = vv.x; v[4*u+1] = vv.y; v[4*u+2] = vv.z; v[4*u+3] = vv.w;
        }
        float s = 0.f;
        #pragma unroll
        for (int u = 0; u < 16; ++u) s += v[u];
        #pragma unroll
        for (int mk = 1; mk < 16; mk <<= 1) s += __shfl_xor(s, mk);
        float mu = s * (1.0f / D);
        float s2 = 0.f;
        #pragma unroll
        for (int u = 0; u < 16; ++u) { v[u] -= mu; s2 += v[u] * v[u]; }
        #pragma unroll
        for (int mk = 1; mk < 16; mk <<= 1) s2 += __shfl_xor(s2, mk);
        float rstd = rsqrtf(s2 * (1.0f / D) + 1e-5f);
        bf16x8 o0, o1;
        #pragma unroll
        for (int u = 0; u < 8; ++u) o0[u] = (__bf16)(v[u] * rstd * gv[u] + bv[u]);
        #pragma unroll
        for (int u = 0; u < 8; ++u) o1[u] = (__bf16)(v[8+u] * rstd * gv[8+u] + bv[8+u]);
        *(bf16x8*)&slds[r][col0]     = o0;
        *(bf16x8*)&slds[r][col0 + 8] = o1;
    }
}

// ---------------- MFMA GEMM core, compile-time K: full unroll (K<=256) or 4x (K=1024) -----
template<int RG, int K>
__device__ __forceinline__ void gemm_tile(
    const __bf16* __restrict__ A, int lda,
    const __bf16* __restrict__ W, int ldb,
    int lane, f32x4 (&acc)[RG][4])
{
    int lr = lane & 15, lk = (lane >> 4) * 8;
    const __bf16* a0 = A + (long)lr * lda + lk;
    const __bf16* b0 = W + (long)lr * ldb + lk;
    const __bf16* b1 = b0 + 16 * ldb;
    const __bf16* b2 = b0 + 32 * ldb;
    const __bf16* b3 = b0 + 48 * ldb;
    constexpr int CH = (K <= 256) ? K : 128;
    for (int kb = 0; kb < K; kb += CH) {
        #pragma unroll
        for (int ku = 0; ku < CH; ku += 32) {
            int k = kb + ku;
            bf16x8 av[RG];
            #pragma unroll
            for (int i = 0; i < RG; ++i) av[i] = *(const bf16x8*)(a0 + i * 16 * lda + k);
            bf16x8 bv0 = *(const bf16x8*)(b0 + k);
            bf16x8 bv1 = *(const bf16x8*)(b1 + k);
            bf16x8 bv2 = *(const bf16x8*)(b2 + k);
            bf16x8 bv3 = *(const bf16x8*)(b3 + k);
            #pragma unroll
            for (int i = 0; i < RG; ++i) {
                acc[i][0] = MFMA16(av[i], bv0, acc[i][0]);
                acc[i][1] = MFMA16(av[i], bv1, acc[i][1]);
                acc[i][2] = MFMA16(av[i], bv2, acc[i][2]);
                acc[i][3] = MFMA16(av[i], bv3, acc[i][3]);
            }
        }
    }
}

#define GEMM_K_DISPATCH(RG, Aexpr, lda, Wexpr, ldb, accv)                        \
    switch (m) {                                                                 \
      case 256: gemm_tile<RG, 256>(Aexpr, lda, Wexpr, ldb, lane, accv); break;   \
      case 128: gemm_tile<RG, 128>(Aexpr, lda, Wexpr, ldb, lane, accv); break;   \
      case 64:  gemm_tile<RG, 64>(Aexpr, lda, Wexpr, ldb, lane, accv); break;    \
      default:  gemm_tile<RG, 32>(Aexpr, lda, Wexpr, ldb, lane, accv); break;    \
    }

// ---------------- fused LN1 + QKV projection (block: 32 rows x 256 cols of one of q/k/v) ----
__global__ __launch_bounds__(256) void qkv_ln_gemm(
    const float* __restrict__ xs,
    const __bf16* __restrict__ qwb, const __bf16* __restrict__ kwb, const __bf16* __restrict__ vwb,
    const float* __restrict__ qb, const float* __restrict__ kb, const float* __restrict__ vb,
    const float* __restrict__ g, const float* __restrict__ bta,
    __bf16* __restrict__ Qb, __bf16* __restrict__ Kb, __bf16* __restrict__ Vt)
{
    int tid = threadIdx.x, lane = tid & 63, wid = tid >> 6;
    int tile = blockIdx.x, which = blockIdx.y, b = blockIdx.z;
    int row0 = tile * 32;
    int m = D >> (row0 >> 8);
    __shared__ __bf16 slds[32][264];
    ln_rows32(xs + ((long)b * T + row0) * D, g, bta, slds, tid);
    __syncthreads();
    const __bf16* W = which == 0 ? qwb : which == 1 ? kwb : vwb;
    const float* bias = which == 0 ? qb : which == 1 ? kb : vb;
    int ncol0 = wid * 64;
    const f32x4 vz = {0.f, 0.f, 0.f, 0.f};
    f32x4 acc[2][4];
    #pragma unroll
    for (int i = 0; i < 2; ++i) { acc[i][0]=vz; acc[i][1]=vz; acc[i][2]=vz; acc[i][3]=vz; }
    GEMM_K_DISPATCH(2, &slds[0][0], 264, W + (long)ncol0 * D, D, acc)
    int lr = lane & 15, rg = (lane >> 4) * 4;
    #pragma unroll
    for (int i = 0; i < 2; ++i) {
        int row = row0 + i * 16 + rg;
        #pragma unroll
        for (int j = 0; j < 4; ++j) {
            int n = ncol0 + j * 16 + lr;
            float bvs = bias[n];
            if (which == 2) {
                bf16x4 pk;
                #pragma unroll
                for (int r = 0; r < 4; ++r) pk[r] = (__bf16)(acc[i][j][r] + bvs);
                *(bf16x4*)&Vt[((long)b * D + n) * T + row] = pk;
            } else if (which == 0) {
                #pragma unroll
                for (int r = 0; r < 4; ++r)   // fold attention scale 2^-4 into Q
                    Qb[((long)b * T + row + r) * D + n] = (__bf16)((acc[i][j][r] + bvs) * 0.0625f);
            } else {
                #pragma unroll
                for (int r = 0; r < 4; ++r)
                    Kb[((long)b * T + row + r) * D + n] = (__bf16)(acc[i][j][r] + bvs);
            }
        }
    }
}

// ---------------- attention: swapped-QK^T MFMA flash, 32 q/wave, 2-deep pipelined kc loop ---
// grid 512; XCD pinning: bid&7 = batch b, so each batch's K/V stays in one XCD's L2.
__global__ __launch_bounds__(256) void attn_mfma(
    const __bf16* __restrict__ Qb, const __bf16* __restrict__ Kb,
    const __bf16* __restrict__ Vt, __bf16* __restrict__ aob)
{
    int bid = blockIdx.x;
    int bh = (bid & 7) * 8 + ((bid >> 3) & 7);
    int qt = bid >> 6;
    int b = bh >> 3, h = bh & 7;
    int lane = threadIdx.x & 63, wave = threadIdx.x >> 6;
    int lr = lane & 15, g = lane >> 4;
    int q0 = qt * 128 + wave * 32;
    __shared__ __bf16 plds[4][32][72];
    const f32x4 vz = {0.f, 0.f, 0.f, 0.f};
    bf16x8 qf[2];
    qf[0] = *(const bf16x8*)&Qb[((long)b * T + q0 + lr) * D + h * DH + g * 8];
    qf[1] = *(const bf16x8*)&Qb[((long)b * T + q0 + 16 + lr) * D + h * DH + g * 8];
    f32x4 acc[2][2] = {{vz, vz}, {vz, vz}};
    float ls[2] = {0.f, 0.f};
    const __bf16* kbase = Kb + (long)b * T * D + h * DH + g * 8;
    const __bf16* vbase = Vt + ((long)b * D + h * DH) * T;

    // register double-buffers (named, statically indexed — no scratch)
    bf16x8 ka[4], va[2][2], kb2[4], vb2[2][2];

#define LOADKV(KF, VF, KC)                                                                \
    {                                                                                     \
        _Pragma("unroll")                                                                 \
        for (int j = 0; j < 4; ++j)                                                       \
            KF[j] = *(const bf16x8*)(kbase + (long)((KC) + 16 * j + lr) * D);             \
        _Pragma("unroll")                                                                 \
        for (int w = 0; w < 2; ++w) {                                                     \
            VF[w][0] = *(const bf16x8*)(vbase + (long)lr * T        + (KC) + 32 * w + 8 * g); \
            VF[w][1] = *(const bf16x8*)(vbase + (long)(16 + lr) * T + (KC) + 32 * w + 8 * g); \
        }                                                                                 \
    }

#define COMPUTE(KF, VF)                                                                   \
    {                                                                                     \
        _Pragma("unroll")                                                                 \
        for (int qi = 0; qi < 2; ++qi) {                                                  \
            _Pragma("unroll")                                                             \
            for (int j = 0; j < 4; ++j) {                                                 \
                f32x4 s = MFMA16(KF[j], qf[qi], vz);                                      \
                float p0 = __expf(s[0]), p1 = __expf(s[1]);                               \
                float p2 = __expf(s[2]), p3 = __expf(s[3]);                               \
                ls[qi] += (p0 + p1) + (p2 + p3);                                          \
                bf16x4 pk;                                                                \
                pk[0] = (__bf16)p0; pk[1] = (__bf16)p1;                                   \
                pk[2] = (__bf16)p2; pk[3] = (__bf16)p3;                                   \
                *(bf16x4*)&plds[wave][qi * 16 + lr][16 * j + 4 * g] = pk;                 \
            }                                                                             \
        }                                                                                 \
        _Pragma("unroll")                                                                 \
        for (int qi = 0; qi < 2; ++qi) {                                                  \
            _Pragma("unroll")                                                             \
            for (int w = 0; w < 2; ++w) {                                                 \
                bf16x8 pa = *(const bf16x8*)&plds[wave][qi * 16 + lr][32 * w + 8 * g];    \
                acc[qi][0] = MFMA16(pa, VF[w][0], acc[qi][0]);                            \
                acc[qi][1] = MFMA16(pa, VF[w][1], acc[qi][1]);                            \
            }                                                                             \
        }                                                                                 \
    }

    LOADKV(ka, va, 0)
    #pragma unroll
    for (int kc = 0; kc < T; kc += 128) {
        LOADKV(kb2, vb2, kc + 64)          // prefetch block n+1 before computing block n
        COMPUTE(ka, va)
        if (kc + 128 < T) LOADKV(ka, va, kc + 128)
        COMPUTE(kb2, vb2)
    }
#undef LOADKV
#undef COMPUTE

    #pragma unroll
    for (int qi = 0; qi < 2; ++qi) {
        ls[qi] += __shfl_xor(ls[qi], 16);
        ls[qi] += __shfl_xor(ls[qi], 32);
        float inv = 1.0f / ls[qi];
        #pragma unroll
        for (int r = 0; r < 4; ++r) {
            float invr = __shfl(inv, 4 * g + r);   // sum for query 4g+r lives at lane lr==4g+r
            long obase = ((long)b * T + q0 + qi * 16 + 4 * g + r) * D + h * DH;
            aob[obase + lr]      = (__bf16)(acc[qi][0][r] * invr);
            aob[obase + 16 + lr] = (__bf16)(acc[qi][1][r] * invr);
        }
    }
}

#define GEMM_PROLOGUE \
    int lane = threadIdx.x & 63, wid = threadIdx.x >> 6; \
    int wm = wid >> 1, wn = wid & 1; \
    int b = blockIdx.z >> 2, e = blockIdx.z & 3; \
    int m = D >> e; \
    const f32x4 vz = {0.f, 0.f, 0.f, 0.f}; \
    f32x4 acc[2][4]; \
    _Pragma("unroll") \
    for (int i = 0; i < 2; ++i) { acc[i][0]=vz; acc[i][1]=vz; acc[i][2]=vz; acc[i][3]=vz; }

// ---------------- O projection GEMM + residual into fp32 xs ----------------
__global__ __launch_bounds__(256) void oproj_gemm(
    const __bf16* __restrict__ aob, const __bf16* __restrict__ owb,
    const float* __restrict__ ob, float* __restrict__ xs)
{
    GEMM_PROLOGUE
    if ((int)blockIdx.y * 128 >= m) return;
    int ncol0 = blockIdx.y * 128 + wn * 64;
    int row0 = e * NPER + blockIdx.x * 64 + wm * 32;
    GEMM_K_DISPATCH(2, aob + ((long)b * T + row0) * D, D, owb + (long)ncol0 * D, D, acc)
    int lr = lane & 15, rg = (lane >> 4) * 4;
    #pragma unroll
    for (int i = 0; i < 2; ++i) {
        int row = row0 + i * 16 + rg;
        #pragma unroll
        for (int j = 0; j < 4; ++j) {
            int n = ncol0 + j * 16 + lr;
            if (n < m) {
                float bv = ob[n];
                #pragma unroll
                for (int r = 0; r < 4; ++r)
                    xs[((long)b * T + row + r) * D + n] += acc[i][j][r] + bv;
            }
        }
    }
}

// ---------------- fused LN2 + MLP layer 1 GEMM + exact gelu -> bf16 inner ----------------
__global__ __launch_bounds__(256) void mlp1_ln_gemm(
    const float* __restrict__ xs, const __bf16* __restrict__ w1b,
    const float* __restrict__ b1, const float* __restrict__ g, const float* __restrict__ bta,
    __bf16* __restrict__ innerb)
{
    int tid = threadIdx.x, lane = tid & 63, wid = tid >> 6;
    int tile = blockIdx.x, fq = blockIdx.y, b = blockIdx.z;
    int row0 = tile * 32;
    int m = D >> (row0 >> 8);
    __shared__ __bf16 slds[32][264];
    ln_rows32(xs + ((long)b * T + row0) * D, g, bta, slds, tid);
    __syncthreads();
    int ncol0 = fq * 256 + wid * 64;
    const f32x4 vz = {0.f, 0.f, 0.f, 0.f};
    f32x4 acc[2][4];
    #pragma unroll
    for (int i = 0; i < 2; ++i) { acc[i][0]=vz; acc[i][1]=vz; acc[i][2]=vz; acc[i][3]=vz; }
    GEMM_K_DISPATCH(2, &slds[0][0], 264, w1b + (long)ncol0 * D, D, acc)
    int lr = lane & 15, rg = (lane >> 4) * 4;
    #pragma unroll
    for (int i = 0; i < 2; ++i) {
        int row = row0 + i * 16 + rg;
        #pragma unroll
        for (int j = 0; j < 4; ++j) {
            int f = ncol0 + j * 16 + lr;
            float bv = b1[f];
            #pragma unroll
            for (int r = 0; r < 4; ++r) {
                float xv = acc[i][j][r] + bv;
                float gl = 0.5f * xv * (1.0f + erff(xv * 0.70710678118654752f));
                innerb[((long)b * T + row + r) * D4 + f] = (__bf16)gl;
            }
        }
    }
}

// ---------------- MLP layer 2 GEMM + sf-scaled residual into fp32 xs ----------------
__global__ __launch_bounds__(256) void mlp2_gemm(
    const __bf16* __restrict__ innerb, const __bf16* __restrict__ w2b,
    const float* __restrict__ b2, const float* __restrict__ rpsel,
    const float* __restrict__ alpha, float* __restrict__ xs)
{
    GEMM_PROLOGUE
    if ((int)blockIdx.y * 128 >= m) return;
    int ncol0 = blockIdx.y * 128 + wn * 64;
    int row0 = e * NPER + blockIdx.x * 64 + wm * 32;
    gemm_tile<2, 1024>(innerb + ((long)b * T + row0) * D4, D4,
                       w2b + (long)ncol0 * D4, D4, lane, acc);
    int lr = lane & 15, rg = (lane >> 4) * 4;
    float a0 = alpha[0];
    #pragma unroll
    for (int i = 0; i < 2; ++i) {
        int row = row0 + i * 16 + rg;
        float sf[4];
        #pragma unroll
        for (int r = 0; r < 4; ++r) sf[r] = a0 * rpsel[(long)b * T + row + r] + 1.0f;
        #pragma unroll
        for (int j = 0; j < 4; ++j) {
            int n = ncol0 + j * 16 + lr;
            if (n < m) {
                float bv = b2[n];
                #pragma unroll
                for (int r = 0; r < 4; ++r)
                    xs[((long)b * T + row + r) * D + n] += sf[r] * (acc[i][j][r] + bv);
            }
        }
    }
}

// ---------------- mean pool (2-stage, deterministic) + head ----------------
__global__ void head_partial(const float* __restrict__ xs, float* __restrict__ part) {
    int c = blockIdx.x, b = blockIdx.y, d = threadIdx.x;
    const float* p = xs + ((long)b * T + c * 128) * D + d;
    float s = 0.f;
    #pragma unroll 8
    for (int i = 0; i < 128; ++i) s += p[(long)i * D];
    part[((long)b * 8 + c) * D + d] = s;
}

__global__ void head_final(const float* __restrict__ part, const float* __restrict__ hw,
                           const float* __restrict__ hb, float* __restrict__ out) {
    int b = blockIdx.x, d = threadIdx.x;
    __shared__ float smean[D];
    float s = 0.f;
    #pragma unroll
    for (int c = 0; c < 8; ++c) s += part[((long)b * 8 + c) * D + d];
    smean[d] = s * (1.0f / T);
    __syncthreads();
    if (d < NC) {
        float acc = hb[d];
        for (int c = 0; c < D; ++c) acc += smean[c] * hw[d * D + c];
        out[b * NC + d] = acc;
    }
}

extern "C" void kernel_launch(void* const* d_in, const int* in_sizes, int n_in,
                              void* d_out, int out_size, void* d_ws, size_t ws_size,
                              hipStream_t stream) {
    const float* x      = (const float*)d_in[0];
    const float* patchw = (const float*)d_in[1];
    const float* patchb = (const float*)d_in[2];
    const float* pos    = (const float*)d_in[3];
    const float* rw     = (const float*)d_in[4];
    const float* rb     = (const float*)d_in[5];
    const float* ln1g   = (const float*)d_in[6];
    const float* ln1b   = (const float*)d_in[7];
    const float* qw     = (const float*)d_in[8];
    const float* qbi    = (const float*)d_in[9];
    const float* kw     = (const float*)d_in[10];
    const float* kbi    = (const float*)d_in[11];
    const float* vw     = (const float*)d_in[12];
    const float* vbi    = (const float*)d_in[13];
    const float* ow     = (const float*)d_in[14];
    const float* obi    = (const float*)d_in[15];
    const float* ln2g   = (const float*)d_in[16];
    const float* ln2b   = (const float*)d_in[17];
    const float* l1w    = (const float*)d_in[18];
    const float* l1b    = (const float*)d_in[19];
    const float* l2w    = (const float*)d_in[20];
    const float* l2b    = (const float*)d_in[21];
    const float* hw     = (const float*)d_in[22];
    const float* hb     = (const float*)d_in[23];
    const float* alpha  = (const float*)d_in[24];

    char* p = (char*)d_ws;
    auto alloc = [&](size_t bytes) { void* r = (void*)p; p += (bytes + 255) & ~(size_t)255; return r; };
    const long NTD = (long)BB * T * D;

    float*  tok    = (float*)alloc(NTD * 4);
    float*  xs     = (float*)alloc(NTD * 4);
    float*  rawp   = (float*)alloc((long)BB * T * E * 4);
    float*  rpsel  = (float*)alloc((long)BB * T * 4);
    int*    perm   = (int*)alloc((long)BB * T * 4);
    float*  part   = (float*)alloc((long)BB * 8 * D * 4);
    __bf16* Qb     = (__bf16*)alloc(NTD * 2);
    __bf16* Kb     = (__bf16*)alloc(NTD * 2);
    __bf16* Vt     = (__bf16*)alloc(NTD * 2);
    __bf16* aob    = (__bf16*)alloc(NTD * 2);
    __bf16* innerb = (__bf16*)alloc((long)BB * T * D4 * 2);
    __bf16* qwb    = (__bf16*)alloc((long)LYR * D * D * 2);
    __bf16* kwb    = (__bf16*)alloc((long)LYR * D * D * 2);
    __bf16* vwb    = (__bf16*)alloc((long)LYR * D * D * 2);
    __bf16* owb    = (__bf16*)alloc((long)LYR * D * D * 2);
    __bf16* w1b    = (__bf16*)alloc((long)LYR * D4 * D * 2);
    __bf16* w2b    = (__bf16*)alloc((long)LYR * D * D4 * 2);

    cast6<<<6144, 256, 0, stream>>>(qw, kw, vw, ow, l1w, l2w, qwb, kwb, vwb, owb, w1b, w2b);

    patch_router<<<dim3(T, BB), 256, 0, stream>>>(x, patchw, patchb, pos, rw, rb, tok, rawp);
    route_topk<<<BB, 1024, 0, stream>>>(rawp, perm, rpsel);
    gather_tokens<<<dim3(T, BB), 256, 0, stream>>>(tok, perm, xs);

    for (int l = 0; l < LYR; ++l) {
        qkv_ln_gemm<<<dim3(32, 3, BB), 256, 0, stream>>>(
            xs, qwb + (long)l * D * D, kwb + (long)l * D * D, vwb + (long)l * D * D,
            qbi + l * D, kbi + l * D, vbi + l * D,
            ln1g + l * D, ln1b + l * D, Qb, Kb, Vt);
        attn_mfma<<<dim3(512), 256, 0, stream>>>(Qb, Kb, Vt, aob);
        oproj_gemm<<<dim3(4, 2, BB * E), 256, 0, stream>>>(
            aob, owb + (long)l * D * D, obi + l * D, xs);
        mlp1_ln_gemm<<<dim3(32, 4, BB), 256, 0, stream>>>(
            xs, w1b + (long)l * D4 * D, l1b + (long)l * D4,
            ln2g + l * D, ln2b + l * D, innerb);
        mlp2_gemm<<<dim3(4, 2, BB * E), 256, 0, stream>>>(
            innerb, w2b + (long)l * D * D4, l2b + l * D, rpsel, alpha, xs);
    }

    head_partial<<<dim3(8, BB), 256, 0, stream>>>(xs, part);
    head_final<<<BB, D, 0, stream>>>(part, hw, hb, (float*)d_out);
}

// Round 8
// 954.261 us; speedup vs baseline: 1.3168x; 1.2779x over previous
//
#include <hip/hip_runtime.h>
#include <math.h>

#define D 256
#define E 4
#define H 8
#define LYR 8
#define IMG 128
#define BB 8
#define NC 10
#define T 1024
#define NPER 256
#define DH 32
#define D4 1024

using bf16x8 = __attribute__((ext_vector_type(8))) __bf16;
using bf16x4 = __attribute__((ext_vector_type(4))) __bf16;
using f32x4  = __attribute__((ext_vector_type(4))) float;

#define MFMA16(a, b, c) __builtin_amdgcn_mfma_f32_16x16x32_bf16((a), (b), (c), 0, 0, 0)

// async global->LDS 16B: HW writes lds_base + lane*16; global src is per-lane.
__device__ __forceinline__ void gload16(const void* g, void* l) {
    __builtin_amdgcn_global_load_lds(
        (const __attribute__((address_space(1))) void*)g,
        (__attribute__((address_space(3))) void*)l, 16, 0, 0);
}

// ---------------- single cast kernel for all 6 weight tensors ----------------
__global__ void cast6(const float* __restrict__ s0, const float* __restrict__ s1,
                      const float* __restrict__ s2, const float* __restrict__ s3,
                      const float* __restrict__ s4, const float* __restrict__ s5,
                      __bf16* __restrict__ d0, __bf16* __restrict__ d1,
                      __bf16* __restrict__ d2, __bf16* __restrict__ d3,
                      __bf16* __restrict__ d4, __bf16* __restrict__ d5) {
    const long A4 = (long)LYR * D * D / 4;
    const long W4 = (long)LYR * D4 * D / 4;
    long i = (long)blockIdx.x * 256 + threadIdx.x;
    const float* s; __bf16* d; long off;
    if (i < 4 * A4) {
        int w = (int)(i / A4); off = i - (long)w * A4;
        s = w == 0 ? s0 : w == 1 ? s1 : w == 2 ? s2 : s3;
        d = w == 0 ? d0 : w == 1 ? d1 : w == 2 ? d2 : d3;
    } else {
        long j = i - 4 * A4;
        int w = (int)(j / W4); off = j - (long)w * W4;
        s = w ? s5 : s4; d = w ? d5 : d4;
    }
    float4 v = ((const float4*)s)[off];
    bf16x4 o;
    o[0] = (__bf16)v.x; o[1] = (__bf16)v.y; o[2] = (__bf16)v.z; o[3] = (__bf16)v.w;
    ((bf16x4*)d)[off] = o;
}

// ---------------- fused patch embed + pos emb + router softmax (fp32, exact) -------------
__global__ void patch_router(const float* __restrict__ x, const float* __restrict__ pw,
                             const float* __restrict__ pb, const float* __restrict__ pos,
                             const float* __restrict__ rw, const float* __restrict__ rb,
                             float* __restrict__ tok, float* __restrict__ rawp) {
    int t = blockIdx.x, b = blockIdx.y, d = threadIdx.x;
    __shared__ float sx[48];
    __shared__ float srow[D];
    __shared__ float slog[4];
    int ph = t >> 5, pwc = t & 31;
    if (d < 48) {
        int c = d >> 4, ij = d & 15, i = ij >> 2, j = ij & 3;
        sx[d] = x[(((long)b * 3 + c) * IMG + (ph * 4 + i)) * IMG + (pwc * 4 + j)];
    }
    __syncthreads();
    float acc = pb[d];
    #pragma unroll
    for (int kk = 0; kk < 48; ++kk) acc += sx[kk] * pw[d * 48 + kk];
    float val = acc + pos[(long)t * D + d];
    tok[((long)b * T + t) * D + d] = val;
    srow[d] = val;
    __syncthreads();
    int wv = d >> 6, lane = d & 63;
    float a = 0.f;
    for (int c = lane; c < D; c += 64) a += srow[c] * rw[wv * D + c];
    for (int off = 32; off; off >>= 1) a += __shfl_down(a, off);
    if (lane == 0) slog[wv] = a + rb[wv];
    __syncthreads();
    if (d == 0) {
        float l0 = slog[0], l1 = slog[1], l2 = slog[2], l3 = slog[3];
        float mx = fmaxf(fmaxf(l0, l1), fmaxf(l2, l3));
        float e0 = __expf(l0 - mx), e1 = __expf(l1 - mx), e2 = __expf(l2 - mx), e3 = __expf(l3 - mx);
        float inv = 1.0f / (e0 + e1 + e2 + e3);
        long row = (long)b * T + t;
        rawp[row * 4 + 0] = e0 * inv;
        rawp[row * 4 + 1] = e1 * inv;
        rawp[row * 4 + 2] = e2 * inv;
        rawp[row * 4 + 3] = e3 * inv;
    }
}

// ---------------- greedy routing via MSB-first radix select (partition-exact) ----------------
__global__ __launch_bounds__(1024) void route_topk(const float* __restrict__ rawp,
                                                   int* __restrict__ perm,
                                                   float* __restrict__ rpsel) {
    int b = blockIdx.x, tid = threadIdx.x;
    int lane = tid & 63, wv = tid >> 6;
    __shared__ unsigned hist[256];
    __shared__ unsigned long long ball[16];
    __shared__ int sb_bin, sb_rem;
    bool assigned = false;
    for (int e = 0; e < E; ++e) {
        float v = rawp[((long)b * T + tid) * E + e];
        unsigned key = assigned ? 0u : __float_as_uint(v);
        unsigned prefix = 0;
        int rem = NPER;
        #pragma unroll
        for (int pass = 3; pass >= 0; --pass) {
            int shift = pass * 8;
            if (tid < 256) hist[tid] = 0;
            __syncthreads();
            bool active = (pass == 3) || ((key >> (shift + 8)) == prefix);
            if (active) atomicAdd(&hist[(key >> shift) & 255], 1u);
            __syncthreads();
            if (tid < 64) {
                unsigned c[4], psum = 0;
                #pragma unroll
                for (int u = 0; u < 4; ++u) { c[u] = hist[tid * 4 + u]; psum += c[u]; }
                unsigned suf = psum;
                #pragma unroll
                for (int off = 1; off < 64; off <<= 1) {
                    unsigned o = __shfl_down(suf, off);
                    if (tid + off < 64) suf += o;
                }
                unsigned El = suf - psum;
                if (El < (unsigned)rem && (unsigned)rem <= suf) {
                    unsigned cab = El;
                    #pragma unroll
                    for (int u = 3; u >= 0; --u) {
                        if ((unsigned)rem > cab && (unsigned)rem <= cab + c[u]) {
                            sb_bin = tid * 4 + u;
                            sb_rem = (int)((unsigned)rem - cab);
                        }
                        cab += c[u];
                    }
                }
            }
            __syncthreads();
            prefix = (prefix << 8) | (unsigned)sb_bin;
            rem = sb_rem;
        }
        unsigned t = prefix;
        bool is_tie = (!assigned) && (key == t);
        unsigned long long mbt = __ballot(is_tie);
        if (lane == 0) ball[wv] = mbt;
        __syncthreads();
        int tierank = 0;
        for (int w2 = 0; w2 < wv; ++w2) tierank += __popcll(ball[w2]);
        tierank += __popcll(mbt & ((1ULL << lane) - 1));
        bool sel = (!assigned) && ((key > t) || (is_tie && tierank < rem));
        __syncthreads();
        unsigned long long mbs = __ballot(sel);
        if (lane == 0) ball[wv] = mbs;
        __syncthreads();
        int rank = 0;
        for (int w2 = 0; w2 < wv; ++w2) rank += __popcll(ball[w2]);
        rank += __popcll(mbs & ((1ULL << lane) - 1));
        if (sel) {
            perm[(long)b * T + e * NPER + rank] = tid;
            rpsel[(long)b * T + e * NPER + rank] = v;
            assigned = true;
        }
        __syncthreads();
    }
}

// ---------------- gather tokens into routed order (fp32) ----------------
__global__ void gather_tokens(const float* __restrict__ tok, const int* __restrict__ perm,
                              float* __restrict__ xs) {
    int slot = blockIdx.x, b = blockIdx.y, d = threadIdx.x;
    int src = perm[(long)b * T + slot];
    xs[((long)b * T + slot) * D + d] = tok[((long)b * T + src) * D + d];
}

// ---------------- LN of 32 rows into padded LDS (16 lanes per row, shuffle reduce) --------
__device__ __forceinline__ void ln_rows32(const float* __restrict__ src,
                                          const float* __restrict__ g,
                                          const float* __restrict__ bta,
                                          __bf16 (*slds)[264], int tid) {
    int sub = tid & 15, rowh = tid >> 4;
    int col0 = sub * 16;
    float gv[16], bv[16];
    #pragma unroll
    for (int u = 0; u < 4; ++u) {
        float4 gg = *(const float4*)&g[col0 + 4 * u];
        float4 bb = *(const float4*)&bta[col0 + 4 * u];
        gv[4*u] = gg.x; gv[4*u+1] = gg.y; gv[4*u+2] = gg.z; gv[4*u+3] = gg.w;
        bv[4*u] = bb.x; bv[4*u+1] = bb.y; bv[4*u+2] = bb.z; bv[4*u+3] = bb.w;
    }
    #pragma unroll
    for (int half = 0; half < 2; ++half) {
        int r = rowh + half * 16;
        const float* rp = src + (long)r * D + col0;
        float v[16];
        #pragma unroll
        for (int u = 0; u < 4; ++u) {
            float4 vv = *(const float4*)&rp[4 * u];
            v[4*u] = vv.x; v[4*u+1] = vv.y; v[4*u+2] = vv.z; v[4*u+3] = vv.w;
        }
        float s = 0.f;
        #pragma unroll
        for (int u = 0; u < 16; ++u) s += v[u];
        #pragma unroll
        for (int mk = 1; mk < 16; mk <<= 1) s += __shfl_xor(s, mk);
        float mu = s * (1.0f / D);
        float s2 = 0.f;
        #pragma unroll
        for (int u = 0; u < 16; ++u) { v[u] -= mu; s2 += v[u] * v[u]; }
        #pragma unroll
        for (int mk = 1; mk < 16; mk <<= 1) s2 += __shfl_xor(s2, mk);
        float rstd = rsqrtf(s2 * (1.0f / D) + 1e-5f);
        bf16x8 o0, o1;
        #pragma unroll
        for (int u = 0; u < 8; ++u) o0[u] = (__bf16)(v[u] * rstd * gv[u] + bv[u]);
        #pragma unroll
        for (int u = 0; u < 8; ++u) o1[u] = (__bf16)(v[8+u] * rstd * gv[8+u] + bv[8+u]);
        *(bf16x8*)&slds[r][col0]     = o0;
        *(bf16x8*)&slds[r][col0 + 8] = o1;
    }
}

// ---------------- MFMA GEMM core, compile-time K: full unroll (K<=256) or 4x (K=1024) -----
template<int RG, int K>
__device__ __forceinline__ void gemm_tile(
    const __bf16* __restrict__ A, int lda,
    const __bf16* __restrict__ W, int ldb,
    int lane, f32x4 (&acc)[RG][4])
{
    int lr = lane & 15, lk = (lane >> 4) * 8;
    const __bf16* a0 = A + (long)lr * lda + lk;
    const __bf16* b0 = W + (long)lr * ldb + lk;
    const __bf16* b1 = b0 + 16 * ldb;
    const __bf16* b2 = b0 + 32 * ldb;
    const __bf16* b3 = b0 + 48 * ldb;
    constexpr int CH = (K <= 256) ? K : 128;
    for (int kb = 0; kb < K; kb += CH) {
        #pragma unroll
        for (int ku = 0; ku < CH; ku += 32) {
            int k = kb + ku;
            bf16x8 av[RG];
            #pragma unroll
            for (int i = 0; i < RG; ++i) av[i] = *(const bf16x8*)(a0 + i * 16 * lda + k);
            bf16x8 bv0 = *(const bf16x8*)(b0 + k);
            bf16x8 bv1 = *(const bf16x8*)(b1 + k);
            bf16x8 bv2 = *(const bf16x8*)(b2 + k);
            bf16x8 bv3 = *(const bf16x8*)(b3 + k);
            #pragma unroll
            for (int i = 0; i < RG; ++i) {
                acc[i][0] = MFMA16(av[i], bv0, acc[i][0]);
                acc[i][1] = MFMA16(av[i], bv1, acc[i][1]);
                acc[i][2] = MFMA16(av[i], bv2, acc[i][2]);
                acc[i][3] = MFMA16(av[i], bv3, acc[i][3]);
            }
        }
    }
}

#define GEMM_K_DISPATCH(RG, Aexpr, lda, Wexpr, ldb, accv)                        \
    switch (m) {                                                                 \
      case 256: gemm_tile<RG, 256>(Aexpr, lda, Wexpr, ldb, lane, accv); break;   \
      case 128: gemm_tile<RG, 128>(Aexpr, lda, Wexpr, ldb, lane, accv); break;   \
      case 64:  gemm_tile<RG, 64>(Aexpr, lda, Wexpr, ldb, lane, accv); break;    \
      default:  gemm_tile<RG, 32>(Aexpr, lda, Wexpr, ldb, lane, accv); break;    \
    }

// ---------------- fused LN1 + QKV projection (block: 32 rows x 256 cols of one of q/k/v) ----
__global__ __launch_bounds__(256) void qkv_ln_gemm(
    const float* __restrict__ xs,
    const __bf16* __restrict__ qwb, const __bf16* __restrict__ kwb, const __bf16* __restrict__ vwb,
    const float* __restrict__ qb, const float* __restrict__ kb, const float* __restrict__ vb,
    const float* __restrict__ g, const float* __restrict__ bta,
    __bf16* __restrict__ Qb, __bf16* __restrict__ Kb, __bf16* __restrict__ Vt)
{
    int tid = threadIdx.x, lane = tid & 63, wid = tid >> 6;
    int tile = blockIdx.x, which = blockIdx.y, b = blockIdx.z;
    int row0 = tile * 32;
    int m = D >> (row0 >> 8);
    __shared__ __bf16 slds[32][264];
    ln_rows32(xs + ((long)b * T + row0) * D, g, bta, slds, tid);
    __syncthreads();
    const __bf16* W = which == 0 ? qwb : which == 1 ? kwb : vwb;
    const float* bias = which == 0 ? qb : which == 1 ? kb : vb;
    int ncol0 = wid * 64;
    const f32x4 vz = {0.f, 0.f, 0.f, 0.f};
    f32x4 acc[2][4];
    #pragma unroll
    for (int i = 0; i < 2; ++i) { acc[i][0]=vz; acc[i][1]=vz; acc[i][2]=vz; acc[i][3]=vz; }
    GEMM_K_DISPATCH(2, &slds[0][0], 264, W + (long)ncol0 * D, D, acc)
    int lr = lane & 15, rg = (lane >> 4) * 4;
    #pragma unroll
    for (int i = 0; i < 2; ++i) {
        int row = row0 + i * 16 + rg;
        #pragma unroll
        for (int j = 0; j < 4; ++j) {
            int n = ncol0 + j * 16 + lr;
            float bvs = bias[n];
            if (which == 2) {
                bf16x4 pk;
                #pragma unroll
                for (int r = 0; r < 4; ++r) pk[r] = (__bf16)(acc[i][j][r] + bvs);
                *(bf16x4*)&Vt[((long)b * D + n) * T + row] = pk;
            } else if (which == 0) {
                #pragma unroll
                for (int r = 0; r < 4; ++r)   // fold attention scale 2^-4 into Q
                    Qb[((long)b * T + row + r) * D + n] = (__bf16)((acc[i][j][r] + bvs) * 0.0625f);
            } else {
                #pragma unroll
                for (int r = 0; r < 4; ++r)
                    Kb[((long)b * T + row + r) * D + n] = (__bf16)(acc[i][j][r] + bvs);
            }
        }
    }
}

// ---------------- attention: swapped-QK^T MFMA flash, 32 q/wave ------------------------------
// K/V tiles staged once per block (4 waves share) via async global_load_lds, double-buffered.
// LDS layout = fragment order (per-lane pre-swizzled global src, linear LDS dest):
//   sK[buf][(j*64+lane)*8]  = K[kc+16j+lr][g*8..+8)      (lane = g*16+lr)
//   sV[buf][((df*2+w2)*64+lane)*8] = Vt[df*16+lr][kc+32w2+8g..+8)
// -> all MFMA fragment reads are lane-linear ds_read_b128 (conflict-free).
__global__ __launch_bounds__(256) void attn_mfma(
    const __bf16* __restrict__ Qb, const __bf16* __restrict__ Kb,
    const __bf16* __restrict__ Vt, __bf16* __restrict__ aob)
{
    int bid = blockIdx.x;
    int bh = (bid & 7) * 8 + ((bid >> 3) & 7);
    int qt = bid >> 6;
    int b = bh >> 3, h = bh & 7;
    int tid = threadIdx.x;
    int lane = tid & 63, wave = tid >> 6;
    int lr = lane & 15, g = lane >> 4;
    int q0 = qt * 128 + wave * 32;
    __shared__ __bf16 plds[4][32][72];
    __shared__ __bf16 sK[2][4 * 64 * 8];
    __shared__ __bf16 sV[2][4 * 64 * 8];
    const f32x4 vz = {0.f, 0.f, 0.f, 0.f};
    bf16x8 qf[2];
    qf[0] = *(const bf16x8*)&Qb[((long)b * T + q0 + lr) * D + h * DH + g * 8];
    qf[1] = *(const bf16x8*)&Qb[((long)b * T + q0 + 16 + lr) * D + h * DH + g * 8];
    f32x4 acc[2][2] = {{vz, vz}, {vz, vz}};
    float ls[2] = {0.f, 0.f};
    // per-lane global sources for this wave's K-segment (seg=wave) and V-segment (seg=wave)
    const __bf16* kseg = Kb + ((long)b * T + 16 * wave + lr) * D + h * DH + g * 8;
    const __bf16* vseg = Vt + ((long)b * D + h * DH + (wave >> 1) * 16 + lr) * T
                            + 32 * (wave & 1) + 8 * g;

#define STAGE(BSEL, KC)                                   \
    {                                                     \
        gload16(kseg + (long)(KC) * D, &sK[BSEL][wave * 512]); \
        gload16(vseg + (KC),           &sV[BSEL][wave * 512]); \
    }

#define COMPUTE(BSEL)                                                                     \
    {                                                                                     \
        bf16x8 kf[4], vf[2][2];                                                           \
        _Pragma("unroll")                                                                 \
        for (int j = 0; j < 4; ++j)                                                       \
            kf[j] = *(const bf16x8*)&sK[BSEL][(j * 64 + lane) * 8];                       \
        _Pragma("unroll")                                                                 \
        for (int w2 = 0; w2 < 2; ++w2)                                                    \
            _Pragma("unroll")                                                             \
            for (int df = 0; df < 2; ++df)                                                \
                vf[w2][df] = *(const bf16x8*)&sV[BSEL][((df * 2 + w2) * 64 + lane) * 8];  \
        _Pragma("unroll")                                                                 \
        for (int qi = 0; qi < 2; ++qi) {                                                  \
            _Pragma("unroll")                                                             \
            for (int j = 0; j < 4; ++j) {                                                 \
                f32x4 s = MFMA16(kf[j], qf[qi], vz);                                      \
                float p0 = __expf(s[0]), p1 = __expf(s[1]);                               \
                float p2 = __expf(s[2]), p3 = __expf(s[3]);                               \
                ls[qi] += (p0 + p1) + (p2 + p3);                                          \
                bf16x4 pk;                                                                \
                pk[0] = (__bf16)p0; pk[1] = (__bf16)p1;                                   \
                pk[2] = (__bf16)p2; pk[3] = (__bf16)p3;                                   \
                *(bf16x4*)&plds[wave][qi * 16 + lr][16 * j + 4 * g] = pk;                 \
            }                                                                             \
        }                                                                                 \
        _Pragma("unroll")                                                                 \
        for (int qi = 0; qi < 2; ++qi) {                                                  \
            _Pragma("unroll")                                                             \
            for (int w2 = 0; w2 < 2; ++w2) {                                              \
                bf16x8 pa = *(const bf16x8*)&plds[wave][qi * 16 + lr][32 * w2 + 8 * g];   \
                acc[qi][0] = MFMA16(pa, vf[w2][0], acc[qi][0]);                           \
                acc[qi][1] = MFMA16(pa, vf[w2][1], acc[qi][1]);                           \
            }                                                                             \
        }                                                                                 \
    }

    STAGE(0, 0)
    __syncthreads();
    int bsel = 0;
    for (int kc = 0; kc < T; kc += 64) {
        if (kc + 64 < T) STAGE(bsel ^ 1, kc + 64)   // async: latency hides under COMPUTE
        COMPUTE(bsel)
        __syncthreads();                            // drains stage + protects buffer reuse
        bsel ^= 1;
    }
#undef STAGE
#undef COMPUTE

    #pragma unroll
    for (int qi = 0; qi < 2; ++qi) {
        ls[qi] += __shfl_xor(ls[qi], 16);
        ls[qi] += __shfl_xor(ls[qi], 32);
        float inv = 1.0f / ls[qi];
        #pragma unroll
        for (int r = 0; r < 4; ++r) {
            float invr = __shfl(inv, 4 * g + r);   // sum for query 4g+r lives at lane lr==4g+r
            long obase = ((long)b * T + q0 + qi * 16 + 4 * g + r) * D + h * DH;
            aob[obase + lr]      = (__bf16)(acc[qi][0][r] * invr);
            aob[obase + 16 + lr] = (__bf16)(acc[qi][1][r] * invr);
        }
    }
}

#define GEMM_PROLOGUE \
    int lane = threadIdx.x & 63, wid = threadIdx.x >> 6; \
    int wm = wid >> 1, wn = wid & 1; \
    int b = blockIdx.z >> 2, e = blockIdx.z & 3; \
    int m = D >> e; \
    const f32x4 vz = {0.f, 0.f, 0.f, 0.f}; \
    f32x4 acc[2][4]; \
    _Pragma("unroll") \
    for (int i = 0; i < 2; ++i) { acc[i][0]=vz; acc[i][1]=vz; acc[i][2]=vz; acc[i][3]=vz; }

// ---------------- O projection GEMM + residual into fp32 xs ----------------
__global__ __launch_bounds__(256) void oproj_gemm(
    const __bf16* __restrict__ aob, const __bf16* __restrict__ owb,
    const float* __restrict__ ob, float* __restrict__ xs)
{
    GEMM_PROLOGUE
    if ((int)blockIdx.y * 128 >= m) return;
    int ncol0 = blockIdx.y * 128 + wn * 64;
    int row0 = e * NPER + blockIdx.x * 64 + wm * 32;
    GEMM_K_DISPATCH(2, aob + ((long)b * T + row0) * D, D, owb + (long)ncol0 * D, D, acc)
    int lr = lane & 15, rg = (lane >> 4) * 4;
    #pragma unroll
    for (int i = 0; i < 2; ++i) {
        int row = row0 + i * 16 + rg;
        #pragma unroll
        for (int j = 0; j < 4; ++j) {
            int n = ncol0 + j * 16 + lr;
            if (n < m) {
                float bv = ob[n];
                #pragma unroll
                for (int r = 0; r < 4; ++r)
                    xs[((long)b * T + row + r) * D + n] += acc[i][j][r] + bv;
            }
        }
    }
}

// ---------------- fused LN2 + MLP layer 1 GEMM + exact gelu -> bf16 inner ----------------
__global__ __launch_bounds__(256) void mlp1_ln_gemm(
    const float* __restrict__ xs, const __bf16* __restrict__ w1b,
    const float* __restrict__ b1, const float* __restrict__ g, const float* __restrict__ bta,
    __bf16* __restrict__ innerb)
{
    int tid = threadIdx.x, lane = tid & 63, wid = tid >> 6;
    int tile = blockIdx.x, fq = blockIdx.y, b = blockIdx.z;
    int row0 = tile * 32;
    int m = D >> (row0 >> 8);
    __shared__ __bf16 slds[32][264];
    ln_rows32(xs + ((long)b * T + row0) * D, g, bta, slds, tid);
    __syncthreads();
    int ncol0 = fq * 256 + wid * 64;
    const f32x4 vz = {0.f, 0.f, 0.f, 0.f};
    f32x4 acc[2][4];
    #pragma unroll
    for (int i = 0; i < 2; ++i) { acc[i][0]=vz; acc[i][1]=vz; acc[i][2]=vz; acc[i][3]=vz; }
    GEMM_K_DISPATCH(2, &slds[0][0], 264, w1b + (long)ncol0 * D, D, acc)
    int lr = lane & 15, rg = (lane >> 4) * 4;
    #pragma unroll
    for (int i = 0; i < 2; ++i) {
        int row = row0 + i * 16 + rg;
        #pragma unroll
        for (int j = 0; j < 4; ++j) {
            int f = ncol0 + j * 16 + lr;
            float bv = b1[f];
            #pragma unroll
            for (int r = 0; r < 4; ++r) {
                float xv = acc[i][j][r] + bv;
                float gl = 0.5f * xv * (1.0f + erff(xv * 0.70710678118654752f));
                innerb[((long)b * T + row + r) * D4 + f] = (__bf16)gl;
            }
        }
    }
}

// ---------------- MLP layer 2 GEMM + sf-scaled residual into fp32 xs ----------------
__global__ __launch_bounds__(256) void mlp2_gemm(
    const __bf16* __restrict__ innerb, const __bf16* __restrict__ w2b,
    const float* __restrict__ b2, const float* __restrict__ rpsel,
    const float* __restrict__ alpha, float* __restrict__ xs)
{
    GEMM_PROLOGUE
    if ((int)blockIdx.y * 128 >= m) return;
    int ncol0 = blockIdx.y * 128 + wn * 64;
    int row0 = e * NPER + blockIdx.x * 64 + wm * 32;
    gemm_tile<2, 1024>(innerb + ((long)b * T + row0) * D4, D4,
                       w2b + (long)ncol0 * D4, D4, lane, acc);
    int lr = lane & 15, rg = (lane >> 4) * 4;
    float a0 = alpha[0];
    #pragma unroll
    for (int i = 0; i < 2; ++i) {
        int row = row0 + i * 16 + rg;
        float sf[4];
        #pragma unroll
        for (int r = 0; r < 4; ++r) sf[r] = a0 * rpsel[(long)b * T + row + r] + 1.0f;
        #pragma unroll
        for (int j = 0; j < 4; ++j) {
            int n = ncol0 + j * 16 + lr;
            if (n < m) {
                float bv = b2[n];
                #pragma unroll
                for (int r = 0; r < 4; ++r)
                    xs[((long)b * T + row + r) * D + n] += sf[r] * (acc[i][j][r] + bv);
            }
        }
    }
}

// ---------------- mean pool (2-stage, deterministic) + head ----------------
__global__ void head_partial(const float* __restrict__ xs, float* __restrict__ part) {
    int c = blockIdx.x, b = blockIdx.y, d = threadIdx.x;
    const float* p = xs + ((long)b * T + c * 128) * D + d;
    float s = 0.f;
    #pragma unroll 8
    for (int i = 0; i < 128; ++i) s += p[(long)i * D];
    part[((long)b * 8 + c) * D + d] = s;
}

__global__ void head_final(const float* __restrict__ part, const float* __restrict__ hw,
                           const float* __restrict__ hb, float* __restrict__ out) {
    int b = blockIdx.x, d = threadIdx.x;
    __shared__ float smean[D];
    float s = 0.f;
    #pragma unroll
    for (int c = 0; c < 8; ++c) s += part[((long)b * 8 + c) * D + d];
    smean[d] = s * (1.0f / T);
    __syncthreads();
    if (d < NC) {
        float acc = hb[d];
        for (int c = 0; c < D; ++c) acc += smean[c] * hw[d * D + c];
        out[b * NC + d] = acc;
    }
}

extern "C" void kernel_launch(void* const* d_in, const int* in_sizes, int n_in,
                              void* d_out, int out_size, void* d_ws, size_t ws_size,
                              hipStream_t stream) {
    const float* x      = (const float*)d_in[0];
    const float* patchw = (const float*)d_in[1];
    const float* patchb = (const float*)d_in[2];
    const float* pos    = (const float*)d_in[3];
    const float* rw     = (const float*)d_in[4];
    const float* rb     = (const float*)d_in[5];
    const float* ln1g   = (const float*)d_in[6];
    const float* ln1b   = (const float*)d_in[7];
    const float* qw     = (const float*)d_in[8];
    const float* qbi    = (const float*)d_in[9];
    const float* kw     = (const float*)d_in[10];
    const float* kbi    = (const float*)d_in[11];
    const float* vw     = (const float*)d_in[12];
    const float* vbi    = (const float*)d_in[13];
    const float* ow     = (const float*)d_in[14];
    const float* obi    = (const float*)d_in[15];
    const float* ln2g   = (const float*)d_in[16];
    const float* ln2b   = (const float*)d_in[17];
    const float* l1w    = (const float*)d_in[18];
    const float* l1b    = (const float*)d_in[19];
    const float* l2w    = (const float*)d_in[20];
    const float* l2b    = (const float*)d_in[21];
    const float* hw     = (const float*)d_in[22];
    const float* hb     = (const float*)d_in[23];
    const float* alpha  = (const float*)d_in[24];

    char* p = (char*)d_ws;
    auto alloc = [&](size_t bytes) { void* r = (void*)p; p += (bytes + 255) & ~(size_t)255; return r; };
    const long NTD = (long)BB * T * D;

    float*  tok    = (float*)alloc(NTD * 4);
    float*  xs     = (float*)alloc(NTD * 4);
    float*  rawp   = (float*)alloc((long)BB * T * E * 4);
    float*  rpsel  = (float*)alloc((long)BB * T * 4);
    int*    perm   = (int*)alloc((long)BB * T * 4);
    float*  part   = (float*)alloc((long)BB * 8 * D * 4);
    __bf16* Qb     = (__bf16*)alloc(NTD * 2);
    __bf16* Kb     = (__bf16*)alloc(NTD * 2);
    __bf16* Vt     = (__bf16*)alloc(NTD * 2);
    __bf16* aob    = (__bf16*)alloc(NTD * 2);
    __bf16* innerb = (__bf16*)alloc((long)BB * T * D4 * 2);
    __bf16* qwb    = (__bf16*)alloc((long)LYR * D * D * 2);
    __bf16* kwb    = (__bf16*)alloc((long)LYR * D * D * 2);
    __bf16* vwb    = (__bf16*)alloc((long)LYR * D * D * 2);
    __bf16* owb    = (__bf16*)alloc((long)LYR * D * D * 2);
    __bf16* w1b    = (__bf16*)alloc((long)LYR * D4 * D * 2);
    __bf16* w2b    = (__bf16*)alloc((long)LYR * D * D4 * 2);

    cast6<<<6144, 256, 0, stream>>>(qw, kw, vw, ow, l1w, l2w, qwb, kwb, vwb, owb, w1b, w2b);

    patch_router<<<dim3(T, BB), 256, 0, stream>>>(x, patchw, patchb, pos, rw, rb, tok, rawp);
    route_topk<<<BB, 1024, 0, stream>>>(rawp, perm, rpsel);
    gather_tokens<<<dim3(T, BB), 256, 0, stream>>>(tok, perm, xs);

    for (int l = 0; l < LYR; ++l) {
        qkv_ln_gemm<<<dim3(32, 3, BB), 256, 0, stream>>>(
            xs, qwb + (long)l * D * D, kwb + (long)l * D * D, vwb + (long)l * D * D,
            qbi + l * D, kbi + l * D, vbi + l * D,
            ln1g + l * D, ln1b + l * D, Qb, Kb, Vt);
        attn_mfma<<<dim3(512), 256, 0, stream>>>(Qb, Kb, Vt, aob);
        oproj_gemm<<<dim3(4, 2, BB * E), 256, 0, stream>>>(
            aob, owb + (long)l * D * D, obi + l * D, xs);
        mlp1_ln_gemm<<<dim3(32, 4, BB), 256, 0, stream>>>(
            xs, w1b + (long)l * D4 * D, l1b + (long)l * D4,
            ln2g + l * D, ln2b + l * D, innerb);
        mlp2_gemm<<<dim3(4, 2, BB * E), 256, 0, stream>>>(
            innerb, w2b + (long)l * D * D4, l2b + l * D, rpsel, alpha, xs);
    }

    head_partial<<<dim3(8, BB), 256, 0, stream>>>(xs, part);
    head_final<<<BB, D, 0, stream>>>(part, hw, hb, (float*)d_out);
}

// Round 9
// 905.765 us; speedup vs baseline: 1.3873x; 1.0535x over previous
//
#include <hip/hip_runtime.h>
#include <math.h>

#define D 256
#define E 4
#define H 8
#define LYR 8
#define IMG 128
#define BB 8
#define NC 10
#define T 1024
#define NPER 256
#define DH 32
#define D4 1024

using bf16x8 = __attribute__((ext_vector_type(8))) __bf16;
using bf16x4 = __attribute__((ext_vector_type(4))) __bf16;
using f32x4  = __attribute__((ext_vector_type(4))) float;

#define MFMA16(a, b, c) __builtin_amdgcn_mfma_f32_16x16x32_bf16((a), (b), (c), 0, 0, 0)

// async global->LDS 16B: HW writes lds_base + lane*16; global src is per-lane.
__device__ __forceinline__ void gload16(const void* g, void* l) {
    __builtin_amdgcn_global_load_lds(
        (const __attribute__((address_space(1))) void*)g,
        (__attribute__((address_space(3))) void*)l, 16, 0, 0);
}

// ---------------- single cast kernel for all 6 weight tensors ----------------
__global__ void cast6(const float* __restrict__ s0, const float* __restrict__ s1,
                      const float* __restrict__ s2, const float* __restrict__ s3,
                      const float* __restrict__ s4, const float* __restrict__ s5,
                      __bf16* __restrict__ d0, __bf16* __restrict__ d1,
                      __bf16* __restrict__ d2, __bf16* __restrict__ d3,
                      __bf16* __restrict__ d4, __bf16* __restrict__ d5) {
    const long A4 = (long)LYR * D * D / 4;
    const long W4 = (long)LYR * D4 * D / 4;
    long i = (long)blockIdx.x * 256 + threadIdx.x;
    const float* s; __bf16* d; long off;
    if (i < 4 * A4) {
        int w = (int)(i / A4); off = i - (long)w * A4;
        s = w == 0 ? s0 : w == 1 ? s1 : w == 2 ? s2 : s3;
        d = w == 0 ? d0 : w == 1 ? d1 : w == 2 ? d2 : d3;
    } else {
        long j = i - 4 * A4;
        int w = (int)(j / W4); off = j - (long)w * W4;
        s = w ? s5 : s4; d = w ? d5 : d4;
    }
    float4 v = ((const float4*)s)[off];
    bf16x4 o;
    o[0] = (__bf16)v.x; o[1] = (__bf16)v.y; o[2] = (__bf16)v.z; o[3] = (__bf16)v.w;
    ((bf16x4*)d)[off] = o;
}

// ---------------- fused patch embed + pos emb + router softmax (fp32, exact) -------------
__global__ void patch_router(const float* __restrict__ x, const float* __restrict__ pw,
                             const float* __restrict__ pb, const float* __restrict__ pos,
                             const float* __restrict__ rw, const float* __restrict__ rb,
                             float* __restrict__ tok, float* __restrict__ rawp) {
    int t = blockIdx.x, b = blockIdx.y, d = threadIdx.x;
    __shared__ float sx[48];
    __shared__ float srow[D];
    __shared__ float slog[4];
    int ph = t >> 5, pwc = t & 31;
    if (d < 48) {
        int c = d >> 4, ij = d & 15, i = ij >> 2, j = ij & 3;
        sx[d] = x[(((long)b * 3 + c) * IMG + (ph * 4 + i)) * IMG + (pwc * 4 + j)];
    }
    __syncthreads();
    float acc = pb[d];
    #pragma unroll
    for (int kk = 0; kk < 48; ++kk) acc += sx[kk] * pw[d * 48 + kk];
    float val = acc + pos[(long)t * D + d];
    tok[((long)b * T + t) * D + d] = val;
    srow[d] = val;
    __syncthreads();
    int wv = d >> 6, lane = d & 63;
    float a = 0.f;
    for (int c = lane; c < D; c += 64) a += srow[c] * rw[wv * D + c];
    for (int off = 32; off; off >>= 1) a += __shfl_down(a, off);
    if (lane == 0) slog[wv] = a + rb[wv];
    __syncthreads();
    if (d == 0) {
        float l0 = slog[0], l1 = slog[1], l2 = slog[2], l3 = slog[3];
        float mx = fmaxf(fmaxf(l0, l1), fmaxf(l2, l3));
        float e0 = __expf(l0 - mx), e1 = __expf(l1 - mx), e2 = __expf(l2 - mx), e3 = __expf(l3 - mx);
        float inv = 1.0f / (e0 + e1 + e2 + e3);
        long row = (long)b * T + t;
        rawp[row * 4 + 0] = e0 * inv;
        rawp[row * 4 + 1] = e1 * inv;
        rawp[row * 4 + 2] = e2 * inv;
        rawp[row * 4 + 3] = e3 * inv;
    }
}

// ---------------- greedy routing via MSB-first radix select (partition-exact) ----------------
__global__ __launch_bounds__(1024) void route_topk(const float* __restrict__ rawp,
                                                   int* __restrict__ perm,
                                                   float* __restrict__ rpsel) {
    int b = blockIdx.x, tid = threadIdx.x;
    int lane = tid & 63, wv = tid >> 6;
    __shared__ unsigned hist[256];
    __shared__ unsigned long long ball[16];
    __shared__ int sb_bin, sb_rem;
    bool assigned = false;
    for (int e = 0; e < E; ++e) {
        float v = rawp[((long)b * T + tid) * E + e];
        unsigned key = assigned ? 0u : __float_as_uint(v);
        unsigned prefix = 0;
        int rem = NPER;
        #pragma unroll
        for (int pass = 3; pass >= 0; --pass) {
            int shift = pass * 8;
            if (tid < 256) hist[tid] = 0;
            __syncthreads();
            bool active = (pass == 3) || ((key >> (shift + 8)) == prefix);
            if (active) atomicAdd(&hist[(key >> shift) & 255], 1u);
            __syncthreads();
            if (tid < 64) {
                unsigned c[4], psum = 0;
                #pragma unroll
                for (int u = 0; u < 4; ++u) { c[u] = hist[tid * 4 + u]; psum += c[u]; }
                unsigned suf = psum;
                #pragma unroll
                for (int off = 1; off < 64; off <<= 1) {
                    unsigned o = __shfl_down(suf, off);
                    if (tid + off < 64) suf += o;
                }
                unsigned El = suf - psum;
                if (El < (unsigned)rem && (unsigned)rem <= suf) {
                    unsigned cab = El;
                    #pragma unroll
                    for (int u = 3; u >= 0; --u) {
                        if ((unsigned)rem > cab && (unsigned)rem <= cab + c[u]) {
                            sb_bin = tid * 4 + u;
                            sb_rem = (int)((unsigned)rem - cab);
                        }
                        cab += c[u];
                    }
                }
            }
            __syncthreads();
            prefix = (prefix << 8) | (unsigned)sb_bin;
            rem = sb_rem;
        }
        unsigned t = prefix;
        bool is_tie = (!assigned) && (key == t);
        unsigned long long mbt = __ballot(is_tie);
        if (lane == 0) ball[wv] = mbt;
        __syncthreads();
        int tierank = 0;
        for (int w2 = 0; w2 < wv; ++w2) tierank += __popcll(ball[w2]);
        tierank += __popcll(mbt & ((1ULL << lane) - 1));
        bool sel = (!assigned) && ((key > t) || (is_tie && tierank < rem));
        __syncthreads();
        unsigned long long mbs = __ballot(sel);
        if (lane == 0) ball[wv] = mbs;
        __syncthreads();
        int rank = 0;
        for (int w2 = 0; w2 < wv; ++w2) rank += __popcll(ball[w2]);
        rank += __popcll(mbs & ((1ULL << lane) - 1));
        if (sel) {
            perm[(long)b * T + e * NPER + rank] = tid;
            rpsel[(long)b * T + e * NPER + rank] = v;
            assigned = true;
        }
        __syncthreads();
    }
}

// ---------------- gather tokens into routed order (fp32) ----------------
__global__ void gather_tokens(const float* __restrict__ tok, const int* __restrict__ perm,
                              float* __restrict__ xs) {
    int slot = blockIdx.x, b = blockIdx.y, d = threadIdx.x;
    int src = perm[(long)b * T + slot];
    xs[((long)b * T + slot) * D + d] = tok[((long)b * T + src) * D + d];
}

// ---------------- LN of 32 rows into padded LDS (16 lanes per row, shuffle reduce) --------
__device__ __forceinline__ void ln_rows32(const float* __restrict__ src,
                                          const float* __restrict__ g,
                                          const float* __restrict__ bta,
                                          __bf16 (*slds)[264], int tid) {
    int sub = tid & 15, rowh = tid >> 4;
    int col0 = sub * 16;
    float gv[16], bv[16];
    #pragma unroll
    for (int u = 0; u < 4; ++u) {
        float4 gg = *(const float4*)&g[col0 + 4 * u];
        float4 bb = *(const float4*)&bta[col0 + 4 * u];
        gv[4*u] = gg.x; gv[4*u+1] = gg.y; gv[4*u+2] = gg.z; gv[4*u+3] = gg.w;
        bv[4*u] = bb.x; bv[4*u+1] = bb.y; bv[4*u+2] = bb.z; bv[4*u+3] = bb.w;
    }
    #pragma unroll
    for (int half = 0; half < 2; ++half) {
        int r = rowh + half * 16;
        const float* rp = src + (long)r * D + col0;
        float v[16];
        #pragma unroll
        for (int u = 0; u < 4; ++u) {
            float4 vv = *(const float4*)&rp[4 * u];
            v[4*u] = vv.x; v[4*u+1] = vv.y; v[4*u+2] = vv.z; v[4*u+3] = vv.w;
        }
        float s = 0.f;
        #pragma unroll
        for (int u = 0; u < 16; ++u) s += v[u];
        #pragma unroll
        for (int mk = 1; mk < 16; mk <<= 1) s += __shfl_xor(s, mk);
        float mu = s * (1.0f / D);
        float s2 = 0.f;
        #pragma unroll
        for (int u = 0; u < 16; ++u) { v[u] -= mu; s2 += v[u] * v[u]; }
        #pragma unroll
        for (int mk = 1; mk < 16; mk <<= 1) s2 += __shfl_xor(s2, mk);
        float rstd = rsqrtf(s2 * (1.0f / D) + 1e-5f);
        bf16x8 o0, o1;
        #pragma unroll
        for (int u = 0; u < 8; ++u) o0[u] = (__bf16)(v[u] * rstd * gv[u] + bv[u]);
        #pragma unroll
        for (int u = 0; u < 8; ++u) o1[u] = (__bf16)(v[8+u] * rstd * gv[8+u] + bv[8+u]);
        *(bf16x8*)&slds[r][col0]     = o0;
        *(bf16x8*)&slds[r][col0 + 8] = o1;
    }
}

// ---------------- MFMA GEMM core, compile-time K: full unroll (K<=256) or 4x (K=1024) -----
template<int RG, int K>
__device__ __forceinline__ void gemm_tile(
    const __bf16* __restrict__ A, int lda,
    const __bf16* __restrict__ W, int ldb,
    int lane, f32x4 (&acc)[RG][4])
{
    int lr = lane & 15, lk = (lane >> 4) * 8;
    const __bf16* a0 = A + (long)lr * lda + lk;
    const __bf16* b0 = W + (long)lr * ldb + lk;
    const __bf16* b1 = b0 + 16 * ldb;
    const __bf16* b2 = b0 + 32 * ldb;
    const __bf16* b3 = b0 + 48 * ldb;
    constexpr int CH = (K <= 256) ? K : 128;
    for (int kb = 0; kb < K; kb += CH) {
        #pragma unroll
        for (int ku = 0; ku < CH; ku += 32) {
            int k = kb + ku;
            bf16x8 av[RG];
            #pragma unroll
            for (int i = 0; i < RG; ++i) av[i] = *(const bf16x8*)(a0 + i * 16 * lda + k);
            bf16x8 bv0 = *(const bf16x8*)(b0 + k);
            bf16x8 bv1 = *(const bf16x8*)(b1 + k);
            bf16x8 bv2 = *(const bf16x8*)(b2 + k);
            bf16x8 bv3 = *(const bf16x8*)(b3 + k);
            #pragma unroll
            for (int i = 0; i < RG; ++i) {
                acc[i][0] = MFMA16(av[i], bv0, acc[i][0]);
                acc[i][1] = MFMA16(av[i], bv1, acc[i][1]);
                acc[i][2] = MFMA16(av[i], bv2, acc[i][2]);
                acc[i][3] = MFMA16(av[i], bv3, acc[i][3]);
            }
        }
    }
}

#define GEMM_K_DISPATCH(RG, Aexpr, lda, Wexpr, ldb, accv)                        \
    switch (m) {                                                                 \
      case 256: gemm_tile<RG, 256>(Aexpr, lda, Wexpr, ldb, lane, accv); break;   \
      case 128: gemm_tile<RG, 128>(Aexpr, lda, Wexpr, ldb, lane, accv); break;   \
      case 64:  gemm_tile<RG, 64>(Aexpr, lda, Wexpr, ldb, lane, accv); break;    \
      default:  gemm_tile<RG, 32>(Aexpr, lda, Wexpr, ldb, lane, accv); break;    \
    }

// flattened per-b wave-tile map for oproj/mlp2: 16-row x 64-col tiles, only active ones.
// per (b): e0: 16rt x 4ct (tau 0..63), e1: 16x2 (64..95), e2: 16x1 (96..111), e3: 16x1 (112..127)
__device__ __forceinline__ void tile_map(int tau, int& e, int& rt, int& ct) {
    if (tau < 64)       { e = 0; rt = tau >> 2; ct = tau & 3; }
    else if (tau < 96)  { e = 1; int t2 = tau - 64; rt = t2 >> 1; ct = t2 & 1; }
    else if (tau < 112) { e = 2; rt = tau - 96;  ct = 0; }
    else                { e = 3; rt = tau - 112; ct = 0; }
}

// ---------------- fused LN1 + QKV projection (block: 32 rows x 256 cols of one of q/k/v) ----
__global__ __launch_bounds__(256) void qkv_ln_gemm(
    const float* __restrict__ xs,
    const __bf16* __restrict__ qwb, const __bf16* __restrict__ kwb, const __bf16* __restrict__ vwb,
    const float* __restrict__ qb, const float* __restrict__ kb, const float* __restrict__ vb,
    const float* __restrict__ g, const float* __restrict__ bta,
    __bf16* __restrict__ Qb, __bf16* __restrict__ Kb, __bf16* __restrict__ Vt)
{
    int tid = threadIdx.x, lane = tid & 63, wid = tid >> 6;
    int tile = blockIdx.x, which = blockIdx.y, b = blockIdx.z;
    int row0 = tile * 32;
    int m = D >> (row0 >> 8);
    __shared__ __bf16 slds[32][264];
    ln_rows32(xs + ((long)b * T + row0) * D, g, bta, slds, tid);
    __syncthreads();
    const __bf16* W = which == 0 ? qwb : which == 1 ? kwb : vwb;
    const float* bias = which == 0 ? qb : which == 1 ? kb : vb;
    int ncol0 = wid * 64;
    const f32x4 vz = {0.f, 0.f, 0.f, 0.f};
    f32x4 acc[2][4];
    #pragma unroll
    for (int i = 0; i < 2; ++i) { acc[i][0]=vz; acc[i][1]=vz; acc[i][2]=vz; acc[i][3]=vz; }
    GEMM_K_DISPATCH(2, &slds[0][0], 264, W + (long)ncol0 * D, D, acc)
    int lr = lane & 15, rg = (lane >> 4) * 4;
    #pragma unroll
    for (int i = 0; i < 2; ++i) {
        int row = row0 + i * 16 + rg;
        #pragma unroll
        for (int j = 0; j < 4; ++j) {
            int n = ncol0 + j * 16 + lr;
            float bvs = bias[n];
            if (which == 2) {
                bf16x4 pk;
                #pragma unroll
                for (int r = 0; r < 4; ++r) pk[r] = (__bf16)(acc[i][j][r] + bvs);
                *(bf16x4*)&Vt[((long)b * D + n) * T + row] = pk;
            } else if (which == 0) {
                #pragma unroll
                for (int r = 0; r < 4; ++r)   // fold attention scale 2^-4 into Q
                    Qb[((long)b * T + row + r) * D + n] = (__bf16)((acc[i][j][r] + bvs) * 0.0625f);
            } else {
                #pragma unroll
                for (int r = 0; r < 4; ++r)
                    Kb[((long)b * T + row + r) * D + n] = (__bf16)(acc[i][j][r] + bvs);
            }
        }
    }
}

// ---------------- attention: swapped-QK^T MFMA flash, 32 q/wave, 2 waves/block --------------
// grid 1024 (16 q-tiles x 64 bh), XCD pinned: bid&7 = batch. K/V staged per block via
// async global_load_lds (fragment order, linear LDS dest), double-buffered; 4 loads/wave/tile.
__global__ __launch_bounds__(128) void attn_mfma(
    const __bf16* __restrict__ Qb, const __bf16* __restrict__ Kb,
    const __bf16* __restrict__ Vt, __bf16* __restrict__ aob)
{
    int bid = blockIdx.x;
    int bh = (bid & 7) * 8 + ((bid >> 3) & 7);
    int qt = bid >> 6;
    int b = bh >> 3, h = bh & 7;
    int tid = threadIdx.x;
    int lane = tid & 63, wave = tid >> 6;     // wave in {0,1}
    int lr = lane & 15, g = lane >> 4;
    int q0 = qt * 64 + wave * 32;
    __shared__ __bf16 plds[2][32][72];
    __shared__ __bf16 sK[2][4 * 64 * 8];
    __shared__ __bf16 sV[2][4 * 64 * 8];
    const f32x4 vz = {0.f, 0.f, 0.f, 0.f};
    bf16x8 qf[2];
    qf[0] = *(const bf16x8*)&Qb[((long)b * T + q0 + lr) * D + h * DH + g * 8];
    qf[1] = *(const bf16x8*)&Qb[((long)b * T + q0 + 16 + lr) * D + h * DH + g * 8];
    f32x4 acc[2][2] = {{vz, vz}, {vz, vz}};
    float ls[2] = {0.f, 0.f};
    // this wave stages K-rows 16*(2w+jj) and V-segments v=2w+jj (jj=0,1)
    int j0 = 2 * wave, j1 = 2 * wave + 1;
    const __bf16* kseg0 = Kb + ((long)b * T + 16 * j0 + lr) * D + h * DH + g * 8;
    const __bf16* kseg1 = Kb + ((long)b * T + 16 * j1 + lr) * D + h * DH + g * 8;
    const __bf16* vseg0 = Vt + ((long)b * D + h * DH + (j0 >> 1) * 16 + lr) * T
                             + 32 * (j0 & 1) + 8 * g;
    const __bf16* vseg1 = Vt + ((long)b * D + h * DH + (j1 >> 1) * 16 + lr) * T
                             + 32 * (j1 & 1) + 8 * g;

#define STAGE(BSEL, KC)                                        \
    {                                                          \
        gload16(kseg0 + (long)(KC) * D, &sK[BSEL][j0 * 512]);  \
        gload16(kseg1 + (long)(KC) * D, &sK[BSEL][j1 * 512]);  \
        gload16(vseg0 + (KC),           &sV[BSEL][j0 * 512]);  \
        gload16(vseg1 + (KC),           &sV[BSEL][j1 * 512]);  \
    }

#define COMPUTE(BSEL)                                                                     \
    {                                                                                     \
        bf16x8 kf[4], vf[2][2];                                                           \
        _Pragma("unroll")                                                                 \
        for (int j = 0; j < 4; ++j)                                                       \
            kf[j] = *(const bf16x8*)&sK[BSEL][(j * 64 + lane) * 8];                       \
        _Pragma("unroll")                                                                 \
        for (int w2 = 0; w2 < 2; ++w2)                                                    \
            _Pragma("unroll")                                                             \
            for (int df = 0; df < 2; ++df)                                                \
                vf[w2][df] = *(const bf16x8*)&sV[BSEL][((df * 2 + w2) * 64 + lane) * 8];  \
        _Pragma("unroll")                                                                 \
        for (int qi = 0; qi < 2; ++qi) {                                                  \
            _Pragma("unroll")                                                             \
            for (int j = 0; j < 4; ++j) {                                                 \
                f32x4 s = MFMA16(kf[j], qf[qi], vz);                                      \
                float p0 = __expf(s[0]), p1 = __expf(s[1]);                               \
                float p2 = __expf(s[2]), p3 = __expf(s[3]);                               \
                ls[qi] += (p0 + p1) + (p2 + p3);                                          \
                bf16x4 pk;                                                                \
                pk[0] = (__bf16)p0; pk[1] = (__bf16)p1;                                   \
                pk[2] = (__bf16)p2; pk[3] = (__bf16)p3;                                   \
                *(bf16x4*)&plds[wave][qi * 16 + lr][16 * j + 4 * g] = pk;                 \
            }                                                                             \
        }                                                                                 \
        _Pragma("unroll")                                                                 \
        for (int qi = 0; qi < 2; ++qi) {                                                  \
            _Pragma("unroll")                                                             \
            for (int w2 = 0; w2 < 2; ++w2) {                                              \
                bf16x8 pa = *(const bf16x8*)&plds[wave][qi * 16 + lr][32 * w2 + 8 * g];   \
                acc[qi][0] = MFMA16(pa, vf[w2][0], acc[qi][0]);                           \
                acc[qi][1] = MFMA16(pa, vf[w2][1], acc[qi][1]);                           \
            }                                                                             \
        }                                                                                 \
    }

    STAGE(0, 0)
    __syncthreads();
    int bsel = 0;
    for (int kc = 0; kc < T; kc += 64) {
        if (kc + 64 < T) STAGE(bsel ^ 1, kc + 64)   // async: latency hides under COMPUTE
        COMPUTE(bsel)
        __syncthreads();                            // drains stage + protects buffer reuse
        bsel ^= 1;
    }
#undef STAGE
#undef COMPUTE

    #pragma unroll
    for (int qi = 0; qi < 2; ++qi) {
        ls[qi] += __shfl_xor(ls[qi], 16);
        ls[qi] += __shfl_xor(ls[qi], 32);
        float inv = 1.0f / ls[qi];
        #pragma unroll
        for (int r = 0; r < 4; ++r) {
            float invr = __shfl(inv, 4 * g + r);   // sum for query 4g+r lives at lane lr==4g+r
            long obase = ((long)b * T + q0 + qi * 16 + 4 * g + r) * D + h * DH;
            aob[obase + lr]      = (__bf16)(acc[qi][0][r] * invr);
            aob[obase + 16 + lr] = (__bf16)(acc[qi][1][r] * invr);
        }
    }
}

// ---------------- O projection GEMM + residual into fp32 xs (flattened wave tiles) ---------
__global__ __launch_bounds__(256) void oproj_gemm(
    const __bf16* __restrict__ aob, const __bf16* __restrict__ owb,
    const float* __restrict__ ob, float* __restrict__ xs)
{
    int tid = threadIdx.x, lane = tid & 63, wid = tid >> 6;
    int gw = blockIdx.x * 4 + wid;            // 0..1023
    int b = gw >> 7, tau = gw & 127;
    int e, rt, ct;
    tile_map(tau, e, rt, ct);
    int m = D >> e;
    int row0 = e * NPER + rt * 16;
    int ncol0 = ct * 64;
    const f32x4 vz = {0.f, 0.f, 0.f, 0.f};
    f32x4 acc[1][4] = {{vz, vz, vz, vz}};
    GEMM_K_DISPATCH(1, aob + ((long)b * T + row0) * D, D, owb + (long)ncol0 * D, D, acc)
    int lr = lane & 15, rg = (lane >> 4) * 4;
    int row = row0 + rg;
    #pragma unroll
    for (int j = 0; j < 4; ++j) {
        int n = ncol0 + j * 16 + lr;
        if (n < m) {
            float bv = ob[n];
            #pragma unroll
            for (int r = 0; r < 4; ++r)
                xs[((long)b * T + row + r) * D + n] += acc[0][j][r] + bv;
        }
    }
}

// ---------------- fused LN2 + MLP layer 1 GEMM + exact gelu -> bf16 inner ----------------
__global__ __launch_bounds__(256) void mlp1_ln_gemm(
    const float* __restrict__ xs, const __bf16* __restrict__ w1b,
    const float* __restrict__ b1, const float* __restrict__ g, const float* __restrict__ bta,
    __bf16* __restrict__ innerb)
{
    int tid = threadIdx.x, lane = tid & 63, wid = tid >> 6;
    int tile = blockIdx.x, fq = blockIdx.y, b = blockIdx.z;
    int row0 = tile * 32;
    int m = D >> (row0 >> 8);
    __shared__ __bf16 slds[32][264];
    ln_rows32(xs + ((long)b * T + row0) * D, g, bta, slds, tid);
    __syncthreads();
    int ncol0 = fq * 256 + wid * 64;
    const f32x4 vz = {0.f, 0.f, 0.f, 0.f};
    f32x4 acc[2][4];
    #pragma unroll
    for (int i = 0; i < 2; ++i) { acc[i][0]=vz; acc[i][1]=vz; acc[i][2]=vz; acc[i][3]=vz; }
    GEMM_K_DISPATCH(2, &slds[0][0], 264, w1b + (long)ncol0 * D, D, acc)
    int lr = lane & 15, rg = (lane >> 4) * 4;
    #pragma unroll
    for (int i = 0; i < 2; ++i) {
        int row = row0 + i * 16 + rg;
        #pragma unroll
        for (int j = 0; j < 4; ++j) {
            int f = ncol0 + j * 16 + lr;
            float bv = b1[f];
            #pragma unroll
            for (int r = 0; r < 4; ++r) {
                float xv = acc[i][j][r] + bv;
                float gl = 0.5f * xv * (1.0f + erff(xv * 0.70710678118654752f));
                innerb[((long)b * T + row + r) * D4 + f] = (__bf16)gl;
            }
        }
    }
}

// ---------------- MLP layer 2 GEMM + sf-scaled residual into fp32 xs (flattened) ----------
__global__ __launch_bounds__(256) void mlp2_gemm(
    const __bf16* __restrict__ innerb, const __bf16* __restrict__ w2b,
    const float* __restrict__ b2, const float* __restrict__ rpsel,
    const float* __restrict__ alpha, float* __restrict__ xs)
{
    int tid = threadIdx.x, lane = tid & 63, wid = tid >> 6;
    int gw = blockIdx.x * 4 + wid;            // 0..1023
    int b = gw >> 7, tau = gw & 127;
    int e, rt, ct;
    tile_map(tau, e, rt, ct);
    int m = D >> e;
    int row0 = e * NPER + rt * 16;
    int ncol0 = ct * 64;
    const f32x4 vz = {0.f, 0.f, 0.f, 0.f};
    f32x4 acc[1][4] = {{vz, vz, vz, vz}};
    gemm_tile<1, 1024>(innerb + ((long)b * T + row0) * D4, D4,
                       w2b + (long)ncol0 * D4, D4, lane, acc);
    int lr = lane & 15, rg = (lane >> 4) * 4;
    int row = row0 + rg;
    float a0 = alpha[0];
    float sf[4];
    #pragma unroll
    for (int r = 0; r < 4; ++r) sf[r] = a0 * rpsel[(long)b * T + row + r] + 1.0f;
    #pragma unroll
    for (int j = 0; j < 4; ++j) {
        int n = ncol0 + j * 16 + lr;
        if (n < m) {
            float bv = b2[n];
            #pragma unroll
            for (int r = 0; r < 4; ++r)
                xs[((long)b * T + row + r) * D + n] += sf[r] * (acc[0][j][r] + bv);
        }
    }
}

// ---------------- mean pool (2-stage, deterministic) + head ----------------
__global__ void head_partial(const float* __restrict__ xs, float* __restrict__ part) {
    int c = blockIdx.x, b = blockIdx.y, d = threadIdx.x;
    const float* p = xs + ((long)b * T + c * 128) * D + d;
    float s = 0.f;
    #pragma unroll 8
    for (int i = 0; i < 128; ++i) s += p[(long)i * D];
    part[((long)b * 8 + c) * D + d] = s;
}

__global__ void head_final(const float* __restrict__ part, const float* __restrict__ hw,
                           const float* __restrict__ hb, float* __restrict__ out) {
    int b = blockIdx.x, d = threadIdx.x;
    __shared__ float smean[D];
    float s = 0.f;
    #pragma unroll
    for (int c = 0; c < 8; ++c) s += part[((long)b * 8 + c) * D + d];
    smean[d] = s * (1.0f / T);
    __syncthreads();
    if (d < NC) {
        float acc = hb[d];
        for (int c = 0; c < D; ++c) acc += smean[c] * hw[d * D + c];
        out[b * NC + d] = acc;
    }
}

extern "C" void kernel_launch(void* const* d_in, const int* in_sizes, int n_in,
                              void* d_out, int out_size, void* d_ws, size_t ws_size,
                              hipStream_t stream) {
    const float* x      = (const float*)d_in[0];
    const float* patchw = (const float*)d_in[1];
    const float* patchb = (const float*)d_in[2];
    const float* pos    = (const float*)d_in[3];
    const float* rw     = (const float*)d_in[4];
    const float* rb     = (const float*)d_in[5];
    const float* ln1g   = (const float*)d_in[6];
    const float* ln1b   = (const float*)d_in[7];
    const float* qw     = (const float*)d_in[8];
    const float* qbi    = (const float*)d_in[9];
    const float* kw     = (const float*)d_in[10];
    const float* kbi    = (const float*)d_in[11];
    const float* vw     = (const float*)d_in[12];
    const float* vbi    = (const float*)d_in[13];
    const float* ow     = (const float*)d_in[14];
    const float* obi    = (const float*)d_in[15];
    const float* ln2g   = (const float*)d_in[16];
    const float* ln2b   = (const float*)d_in[17];
    const float* l1w    = (const float*)d_in[18];
    const float* l1b    = (const float*)d_in[19];
    const float* l2w    = (const float*)d_in[20];
    const float* l2b    = (const float*)d_in[21];
    const float* hw     = (const float*)d_in[22];
    const float* hb     = (const float*)d_in[23];
    const float* alpha  = (const float*)d_in[24];

    char* p = (char*)d_ws;
    auto alloc = [&](size_t bytes) { void* r = (void*)p; p += (bytes + 255) & ~(size_t)255; return r; };
    const long NTD = (long)BB * T * D;

    float*  tok    = (float*)alloc(NTD * 4);
    float*  xs     = (float*)alloc(NTD * 4);
    float*  rawp   = (float*)alloc((long)BB * T * E * 4);
    float*  rpsel  = (float*)alloc((long)BB * T * 4);
    int*    perm   = (int*)alloc((long)BB * T * 4);
    float*  part   = (float*)alloc((long)BB * 8 * D * 4);
    __bf16* Qb     = (__bf16*)alloc(NTD * 2);
    __bf16* Kb     = (__bf16*)alloc(NTD * 2);
    __bf16* Vt     = (__bf16*)alloc(NTD * 2);
    __bf16* aob    = (__bf16*)alloc(NTD * 2);
    __bf16* innerb = (__bf16*)alloc((long)BB * T * D4 * 2);
    __bf16* qwb    = (__bf16*)alloc((long)LYR * D * D * 2);
    __bf16* kwb    = (__bf16*)alloc((long)LYR * D * D * 2);
    __bf16* vwb    = (__bf16*)alloc((long)LYR * D * D * 2);
    __bf16* owb    = (__bf16*)alloc((long)LYR * D * D * 2);
    __bf16* w1b    = (__bf16*)alloc((long)LYR * D4 * D * 2);
    __bf16* w2b    = (__bf16*)alloc((long)LYR * D * D4 * 2);

    cast6<<<6144, 256, 0, stream>>>(qw, kw, vw, ow, l1w, l2w, qwb, kwb, vwb, owb, w1b, w2b);

    patch_router<<<dim3(T, BB), 256, 0, stream>>>(x, patchw, patchb, pos, rw, rb, tok, rawp);
    route_topk<<<BB, 1024, 0, stream>>>(rawp, perm, rpsel);
    gather_tokens<<<dim3(T, BB), 256, 0, stream>>>(tok, perm, xs);

    for (int l = 0; l < LYR; ++l) {
        qkv_ln_gemm<<<dim3(32, 3, BB), 256, 0, stream>>>(
            xs, qwb + (long)l * D * D, kwb + (long)l * D * D, vwb + (long)l * D * D,
            qbi + l * D, kbi + l * D, vbi + l * D,
            ln1g + l * D, ln1b + l * D, Qb, Kb, Vt);
        attn_mfma<<<dim3(1024), 128, 0, stream>>>(Qb, Kb, Vt, aob);
        oproj_gemm<<<dim3(256), 256, 0, stream>>>(
            aob, owb + (long)l * D * D, obi + l * D, xs);
        mlp1_ln_gemm<<<dim3(32, 4, BB), 256, 0, stream>>>(
            xs, w1b + (long)l * D4 * D, l1b + (long)l * D4,
            ln2g + l * D, ln2b + l * D, innerb);
        mlp2_gemm<<<dim3(256), 256, 0, stream>>>(
            innerb, w2b + (long)l * D * D4, l2b + l * D, rpsel, alpha, xs);
    }

    head_partial<<<dim3(8, BB), 256, 0, stream>>>(xs, part);
    head_final<<<BB, D, 0, stream>>>(part, hw, hb, (float*)d_out);
}